// Round 2
// baseline (1413.809 us; speedup 1.0000x reference)
//
#include <hip/hip_runtime.h>
#include <hip/hip_bf16.h>
#include <math.h>
#include <cstdint>

typedef __bf16 bf16_t;
typedef bf16_t bf16x8 __attribute__((ext_vector_type(8)));
typedef bf16_t bf16x4 __attribute__((ext_vector_type(4)));
typedef bf16_t bf16x2 __attribute__((ext_vector_type(2)));
typedef float f32x4 __attribute__((ext_vector_type(4)));
typedef float f32x2 __attribute__((ext_vector_type(2)));

#define S_LEN 2048
#define DMODEL 1024
#define NLAYER 4
#define NHEAD 4
#define INNER 2048
#define DHEAD 512
#define NBLK 512
#define UPCOLS 4096
#define GIN 6144

// ---------------- zero f32 buffer ----------------
__global__ void zero_f32(float* __restrict__ p, int n) {
  int i = blockIdx.x * 256 + threadIdx.x;
  if (i < n) p[i] = 0.f;
}

// ---------------- convert f32 -> bf16 (vectorized, grid-stride) ----------------
__global__ __launch_bounds__(256) void cvt_f32_bf16(const float* __restrict__ in,
                                                    bf16_t* __restrict__ out, int n4) {
  int i = blockIdx.x * 256 + threadIdx.x;
  int stride = gridDim.x * 256;
  for (; i < n4; i += stride) {
    f32x4 v = ((const f32x4*)in)[i];
    bf16x4 o;
    #pragma unroll
    for (int j = 0; j < 4; j++) o[j] = (bf16_t)v[j];
    ((bf16x4*)out)[i] = o;
  }
}

// ---------------- LayerNorm (D=1024) -> bf16 ----------------
__global__ __launch_bounds__(256) void ln_kernel(const float* __restrict__ X,
                                                 const float* __restrict__ w,
                                                 bf16_t* __restrict__ out) {
  int s = blockIdx.x;
  int t = threadIdx.x;
  f32x4 v = ((const f32x4*)(X + (size_t)s * DMODEL))[t];
  float s1 = v[0] + v[1] + v[2] + v[3];
  float s2 = v[0]*v[0] + v[1]*v[1] + v[2]*v[2] + v[3]*v[3];
  __shared__ float b1[4], b2[4];
  #pragma unroll
  for (int off = 32; off; off >>= 1) { s1 += __shfl_xor(s1, off); s2 += __shfl_xor(s2, off); }
  if ((t & 63) == 0) { b1[t >> 6] = s1; b2[t >> 6] = s2; }
  __syncthreads();
  float tot1 = b1[0] + b1[1] + b1[2] + b1[3];
  float tot2 = b2[0] + b2[1] + b2[2] + b2[3];
  float mu = tot1 * (1.f / DMODEL);
  float var = tot2 * (1.f / DMODEL) - mu * mu;
  float rs = rsqrtf(var + 1e-5f);
  bf16x4 o;
  #pragma unroll
  for (int j = 0; j < 4; j++) o[j] = (bf16_t)((v[j] - mu) * rs * w[t * 4 + j]);
  ((bf16x4*)(out + (size_t)s * DMODEL))[t] = o;
}

// ---------------- causal conv(K=4)+silu + blockwise q/k/v ----------------
__global__ __launch_bounds__(256) void conv_qkv_kernel(
    const float* __restrict__ UP, const float* __restrict__ cw, const float* __restrict__ cb,
    const float* __restrict__ qw, const float* __restrict__ kw, const float* __restrict__ vw,
    float* __restrict__ XC, bf16_t* __restrict__ Q, bf16_t* __restrict__ Kb, bf16_t* __restrict__ V) {
  int s = blockIdx.y;
  int n = blockIdx.x * 256 + threadIdx.x;  // 0..511
  int c0 = n * 4;
  f32x4 zero4 = {};
  f32x4 xm[4];
  #pragma unroll
  for (int k = 0; k < 4; k++) {
    int sr = s + k - 3;
    xm[k] = (sr >= 0) ? *(const f32x4*)(UP + (size_t)sr * UPCOLS + c0) : zero4;
  }
  f32x4 cbv = *(const f32x4*)(cb + c0);
  float xc[4];
  #pragma unroll
  for (int d = 0; d < 4; d++) {
    f32x4 wv = *(const f32x4*)(cw + (size_t)(c0 + d) * 4);
    float a = cbv[d];
    #pragma unroll
    for (int k = 0; k < 4; k++) a += wv[k] * xm[k][d];
    xc[d] = a / (1.f + __expf(-a));  // silu
  }
  f32x4 xcv; xcv[0]=xc[0]; xcv[1]=xc[1]; xcv[2]=xc[2]; xcv[3]=xc[3];
  *(f32x4*)(XC + (size_t)s * INNER + c0) = xcv;
  bf16x4 qo, ko, vo;
  #pragma unroll
  for (int o = 0; o < 4; o++) {
    float aq = 0, ak = 0, av = 0;
    #pragma unroll
    for (int d = 0; d < 4; d++) {
      aq += qw[n * 16 + o * 4 + d] * xc[d];
      ak += kw[n * 16 + o * 4 + d] * xc[d];
      av += vw[n * 16 + o * 4 + d] * xm[3][d];  // v from pre-conv xm
    }
    qo[o] = (bf16_t)aq; ko[o] = (bf16_t)ak; vo[o] = (bf16_t)av;
  }
  ((bf16x4*)(Q  + (size_t)s * INNER))[n] = qo;
  ((bf16x4*)(Kb + (size_t)s * INNER))[n] = ko;
  ((bf16x4*)(V  + (size_t)s * INNER))[n] = vo;
}

// ---------------- bf16 transpose 2048x2048 ----------------
__global__ __launch_bounds__(256) void transpose_bf16(const bf16_t* __restrict__ in,
                                                      bf16_t* __restrict__ out) {
  __shared__ bf16_t tile[32][33];
  int c0 = blockIdx.x * 32, r0 = blockIdx.y * 32;
  int tx = threadIdx.x & 31, ty = threadIdx.x >> 5;
  #pragma unroll
  for (int i = ty; i < 32; i += 8) tile[i][tx] = in[(size_t)(r0 + i) * INNER + c0 + tx];
  __syncthreads();
  #pragma unroll
  for (int i = ty; i < 32; i += 8) out[(size_t)(c0 + i) * S_LEN + r0 + tx] = tile[tx][i];
}

// ---------------- input/forget gate logits ----------------
__global__ __launch_bounds__(256) void gates_kernel(
    const bf16_t* __restrict__ Q, const bf16_t* __restrict__ K, const bf16_t* __restrict__ V,
    const float* __restrict__ igw, const float* __restrict__ igb,
    const float* __restrict__ fgw, const float* __restrict__ fgb,
    float* __restrict__ IG, float* __restrict__ FG) {
  int s = blockIdx.x;
  float pi[NHEAD] = {0, 0, 0, 0}, pf[NHEAD] = {0, 0, 0, 0};
  for (int e = threadIdx.x; e < GIN; e += 256) {
    float g;
    if (e < INNER)            g = (float)Q[(size_t)s * INNER + e];
    else if (e < 2 * INNER)   g = (float)K[(size_t)s * INNER + e - INNER];
    else                      g = (float)V[(size_t)s * INNER + e - 2 * INNER];
    #pragma unroll
    for (int h = 0; h < NHEAD; h++) {
      pi[h] += g * igw[h * GIN + e];
      pf[h] += g * fgw[h * GIN + e];
    }
  }
  __shared__ float red[8][4];
  #pragma unroll
  for (int h = 0; h < NHEAD; h++) {
    float a = pi[h], b = pf[h];
    #pragma unroll
    for (int off = 32; off; off >>= 1) { a += __shfl_xor(a, off); b += __shfl_xor(b, off); }
    if ((threadIdx.x & 63) == 0) { red[h][threadIdx.x >> 6] = a; red[h + 4][threadIdx.x >> 6] = b; }
  }
  __syncthreads();
  if (threadIdx.x < NHEAD) {
    int h = threadIdx.x;
    IG[h * S_LEN + s] = red[h][0] + red[h][1] + red[h][2] + red[h][3] + igb[h];
    FG[h * S_LEN + s] = red[h + 4][0] + red[h + 4][1] + red[h + 4][2] + red[h + 4][3] + fgb[h];
  }
}

// ---------------- per-head scan: cs=cumsum(logsig(fg)), a=ig-cs, pm=prefmax(a), nf=exp(-(cs+pm)) ----
__global__ __launch_bounds__(256) void scan_kernel(const float* __restrict__ IG,
                                                   const float* __restrict__ FG,
                                                   float* __restrict__ AV, float* __restrict__ PM,
                                                   float* __restrict__ NF) {
  int h = blockIdx.x;
  int tid = threadIdx.x;
  const float* fg = FG + h * S_LEN;
  const float* ig = IG + h * S_LEN;
  float cs[8];
  float run = 0.f;
  #pragma unroll
  for (int i = 0; i < 8; i++) {
    float x = fg[tid * 8 + i];
    float l = (x >= 0.f) ? -log1pf(__expf(-x)) : (x - log1pf(__expf(x)));
    run += l; cs[i] = run;
  }
  __shared__ float sb[256];
  sb[tid] = run;
  __syncthreads();
  for (int off = 1; off < 256; off <<= 1) {
    float add = (tid >= off) ? sb[tid - off] : 0.f;
    __syncthreads();
    sb[tid] += add;
    __syncthreads();
  }
  float base = sb[tid] - run;  // exclusive prefix sum
  float a[8];
  float runm = -__builtin_inff();
  #pragma unroll
  for (int i = 0; i < 8; i++) {
    cs[i] += base;
    a[i] = ig[tid * 8 + i] - cs[i];
    runm = fmaxf(runm, a[i]);
  }
  __syncthreads();
  sb[tid] = runm;
  __syncthreads();
  for (int off = 1; off < 256; off <<= 1) {
    float other = (tid >= off) ? sb[tid - off] : -__builtin_inff();
    __syncthreads();
    sb[tid] = fmaxf(sb[tid], other);
    __syncthreads();
  }
  float rm = (tid == 0) ? -__builtin_inff() : sb[tid - 1];  // exclusive prefix max
  #pragma unroll
  for (int i = 0; i < 8; i++) {
    rm = fmaxf(rm, a[i]);
    AV[h * S_LEN + tid * 8 + i] = a[i];
    PM[h * S_LEN + tid * 8 + i] = rm;
    NF[h * S_LEN + tid * 8 + i] = __expf(-(cs[i] + rm));
  }
}

// ---------------- n = max(|nraw|, nf); scale = 1/(n+1e-6) ----------------
__global__ void scale_kernel(const float* __restrict__ nraw, const float* __restrict__ nf,
                             float* __restrict__ scale, int n) {
  int i = blockIdx.x * 256 + threadIdx.x;
  if (i < n) scale[i] = 1.f / (fmaxf(fabsf(nraw[i]), nf[i]) + 1e-6f);
}

// ---------------- per-head LN over DH + skip*xc, * silu(z) -> bf16 ----------------
__global__ __launch_bounds__(256) void onorm_kernel(
    const float* __restrict__ H, const float* __restrict__ XC, const float* __restrict__ UP,
    const float* __restrict__ onw, const float* __restrict__ skipw, bf16_t* __restrict__ OUT) {
  int h = blockIdx.x, s = blockIdx.y;
  int c = h * DHEAD + threadIdx.x * 2;
  f32x2 v = *(const f32x2*)(H + (size_t)s * INNER + c);
  float s1 = v[0] + v[1], s2 = v[0] * v[0] + v[1] * v[1];
  __shared__ float b1[4], b2[4];
  #pragma unroll
  for (int off = 32; off; off >>= 1) { s1 += __shfl_xor(s1, off); s2 += __shfl_xor(s2, off); }
  if ((threadIdx.x & 63) == 0) { b1[threadIdx.x >> 6] = s1; b2[threadIdx.x >> 6] = s2; }
  __syncthreads();
  float tot1 = b1[0] + b1[1] + b1[2] + b1[3];
  float tot2 = b2[0] + b2[1] + b2[2] + b2[3];
  float mu = tot1 * (1.f / DHEAD);
  float var = tot2 * (1.f / DHEAD) - mu * mu;
  float rs = rsqrtf(var + 1e-5f);
  bf16x2 o;
  #pragma unroll
  for (int j = 0; j < 2; j++) {
    float val = (v[j] - mu) * rs * onw[c + j] + skipw[c + j] * XC[(size_t)s * INNER + c + j];
    float z = UP[(size_t)s * UPCOLS + INNER + c + j];
    val *= z / (1.f + __expf(-z));
    o[j] = (bf16_t)val;
  }
  *(bf16x2*)(OUT + (size_t)s * INNER + c) = o;
}

// ---------------- reward/term: row dot over D ----------------
__global__ __launch_bounds__(256) void rt_kernel(
    const float* __restrict__ R1, const float* __restrict__ T1,
    const float* __restrict__ r2w, const float* __restrict__ r2b,
    const float* __restrict__ t2w, const float* __restrict__ t2b,
    float* __restrict__ outR, float* __restrict__ outT) {
  int s = blockIdx.x, t = threadIdx.x;
  f32x4 a = ((const f32x4*)(R1 + (size_t)s * DMODEL))[t];
  f32x4 b = ((const f32x4*)(T1 + (size_t)s * DMODEL))[t];
  f32x4 w1 = ((const f32x4*)r2w)[t];
  f32x4 w2 = ((const f32x4*)t2w)[t];
  float pr = a[0]*w1[0] + a[1]*w1[1] + a[2]*w1[2] + a[3]*w1[3];
  float pt = b[0]*w2[0] + b[1]*w2[1] + b[2]*w2[2] + b[3]*w2[3];
  __shared__ float rb[4], tb[4];
  #pragma unroll
  for (int off = 32; off; off >>= 1) { pr += __shfl_xor(pr, off); pt += __shfl_xor(pt, off); }
  if ((t & 63) == 0) { rb[t >> 6] = pr; tb[t >> 6] = pt; }
  __syncthreads();
  if (t == 0) {
    outR[s] = rb[0] + rb[1] + rb[2] + rb[3] + r2b[0];
    outT[s] = tb[0] + tb[1] + tb[2] + tb[3] + t2b[0];
  }
}

// ---------------- bf16 MFMA NT GEMM, 128x128 tile, BK=32, 4 waves ----------------
// MODE 0: C = A*B^T            MODE 1: C += A*B^T      MODE 2: C = A*B^T + bias[n]
// MODE 3: decay epilogue -> P bf16 + row-sum atomics (QK^T)
// MODE 4: C = (A*B^T) * scale[row]  with causal K-limit  (PV)
#define BM 128
#define BN 128
#define BKK 32
#define LDSTR 40

template <int MODE>
__global__ __launch_bounds__(256) void gemm_kernel(
    const bf16_t* __restrict__ A, int lda, long long sAz,
    const bf16_t* __restrict__ B, int ldb, long long sBz,
    float* __restrict__ C, int ldc, long long sCz,
    bf16_t* __restrict__ P, long long sPz,
    int M, int N, int K,
    const float* __restrict__ bias,
    const float* __restrict__ avec, const float* __restrict__ pmvec,
    float* __restrict__ nraw,
    const float* __restrict__ scalev, long long sVz, int causal) {
  int z = blockIdx.z;
  int m0 = blockIdx.y * BM;
  int n0 = blockIdx.x * BN;
  if (MODE == 3 && n0 > m0 + (BM - 1)) return;  // fully-masked causal tile
  A += z * sAz; B += z * sBz;
  int Keff = K;
  if (MODE == 4 && causal) { int ke = m0 + BM; Keff = ke < K ? ke : K; }

  __shared__ bf16_t As[BM][LDSTR];
  __shared__ bf16_t Bs[BN][LDSTR];

  int tid = threadIdx.x;
  int lane = tid & 63;
  int wave = tid >> 6;
  int wr = wave >> 1, wc = wave & 1;
  int l15 = lane & 15, lk = lane >> 4;
  int srow = tid >> 2, scol = (tid & 3) * 8;

  f32x4 acc[4][4] = {};

  for (int k0 = 0; k0 < Keff; k0 += BKK) {
    *(bf16x8*)(&As[srow][scol])      = *(const bf16x8*)(A + (size_t)(m0 + srow) * lda + k0 + scol);
    *(bf16x8*)(&As[srow + 64][scol]) = *(const bf16x8*)(A + (size_t)(m0 + srow + 64) * lda + k0 + scol);
    *(bf16x8*)(&Bs[srow][scol])      = *(const bf16x8*)(B + (size_t)(n0 + srow) * ldb + k0 + scol);
    *(bf16x8*)(&Bs[srow + 64][scol]) = *(const bf16x8*)(B + (size_t)(n0 + srow + 64) * ldb + k0 + scol);
    __syncthreads();
    bf16x8 af[4], bfv[4];
    #pragma unroll
    for (int m = 0; m < 4; m++) af[m] = *(const bf16x8*)(&As[wr * 64 + m * 16 + l15][lk * 8]);
    #pragma unroll
    for (int n = 0; n < 4; n++) bfv[n] = *(const bf16x8*)(&Bs[wc * 64 + n * 16 + l15][lk * 8]);
    #pragma unroll
    for (int m = 0; m < 4; m++)
      #pragma unroll
      for (int n = 0; n < 4; n++)
        acc[m][n] = __builtin_amdgcn_mfma_f32_16x16x32_bf16(af[m], bfv[n], acc[m][n], 0, 0, 0);
    __syncthreads();
  }

  int rbase = m0 + wr * 64;
  int cbase = n0 + wc * 64;
  if (MODE == 3) {
    const float* av = avec + z * sVz;
    const float* pv = pmvec + z * sVz;
    float* nr = nraw + z * sVz;
    bf16_t* Pp = P + z * sPz;
    const float ISQ = 0.04419417382415922f;  // 1/sqrt(512)
    #pragma unroll
    for (int m = 0; m < 4; m++) {
      float rsum[4] = {0, 0, 0, 0};
      #pragma unroll
      for (int n = 0; n < 4; n++) {
        int cg = cbase + n * 16 + l15;
        float aexp = av[cg];
        #pragma unroll
        for (int r = 0; r < 4; r++) {
          int rg = rbase + m * 16 + lk * 4 + r;
          float val = 0.f;
          if (cg <= rg) val = acc[m][n][r] * ISQ * __expf(aexp - pv[rg]);
          Pp[(size_t)rg * ldc + cg] = (bf16_t)val;
          rsum[r] += val;
        }
      }
      #pragma unroll
      for (int r = 0; r < 4; r++) {
        float v = rsum[r];
        v += __shfl_xor(v, 1); v += __shfl_xor(v, 2); v += __shfl_xor(v, 4); v += __shfl_xor(v, 8);
        if (l15 == 0) atomicAdd(&nr[rbase + m * 16 + lk * 4 + r], v);
      }
    }
  } else {
    #pragma unroll
    for (int m = 0; m < 4; m++) {
      #pragma unroll
      for (int r = 0; r < 4; r++) {
        int rg = rbase + m * 16 + lk * 4 + r;
        float rowscale = (MODE == 4) ? scalev[z * sVz + rg] : 1.f;
        #pragma unroll
        for (int n = 0; n < 4; n++) {
          int cg = cbase + n * 16 + l15;
          size_t idx = (size_t)z * sCz + (size_t)rg * ldc + cg;
          float v = acc[m][n][r];
          if (MODE == 1) C[idx] += v;
          else if (MODE == 2) C[idx] = v + bias[cg];
          else if (MODE == 4) C[idx] = v * rowscale;
          else C[idx] = v;
        }
      }
    }
  }
}

extern "C" void kernel_launch(void* const* d_in, const int* in_sizes, int n_in,
                              void* d_out, int out_size, void* d_ws, size_t ws_size,
                              hipStream_t stream) {
  const float* tokens = (const float*)d_in[0];
  const float* ln_w   = (const float*)d_in[1];
  const float* up_w   = (const float*)d_in[2];
  const float* conv_w = (const float*)d_in[3];
  const float* conv_b = (const float*)d_in[4];
  const float* q_w    = (const float*)d_in[5];
  const float* k_w    = (const float*)d_in[6];
  const float* v_w    = (const float*)d_in[7];
  const float* ig_w   = (const float*)d_in[8];
  const float* ig_b   = (const float*)d_in[9];
  const float* fg_w   = (const float*)d_in[10];
  const float* fg_b   = (const float*)d_in[11];
  const float* skipw  = (const float*)d_in[12];
  const float* onormw = (const float*)d_in[13];
  const float* down_w = (const float*)d_in[14];
  const float* post_w = (const float*)d_in[15];
  const float* lat_w  = (const float*)d_in[16];
  const float* lat_b  = (const float*)d_in[17];
  const float* r1_w   = (const float*)d_in[18];
  const float* r1_b   = (const float*)d_in[19];
  const float* r2_w   = (const float*)d_in[20];
  const float* r2_b   = (const float*)d_in[21];
  const float* t1_w   = (const float*)d_in[22];
  const float* t1_b   = (const float*)d_in[23];
  const float* t2_w   = (const float*)d_in[24];
  const float* t2_b   = (const float*)d_in[25];

  char* ws = (char*)d_ws;
  size_t off = 0;
  auto alloc = [&](size_t bytes) -> char* {
    char* p = ws + off;
    off += (bytes + 255) & ~(size_t)255;
    return p;
  };
  float*  X    = (float*)alloc((size_t)S_LEN * DMODEL * 4);
  float*  UP   = (float*)alloc((size_t)S_LEN * UPCOLS * 4);
  float*  XC   = (float*)alloc((size_t)S_LEN * INNER * 4);
  float*  Hbuf = (float*)alloc((size_t)S_LEN * INNER * 4);
  bf16_t* XN   = (bf16_t*)alloc((size_t)S_LEN * DMODEL * 2);
  bf16_t* Qb   = (bf16_t*)alloc((size_t)S_LEN * INNER * 2);
  bf16_t* Kb   = (bf16_t*)alloc((size_t)S_LEN * INNER * 2);
  bf16_t* Vb   = (bf16_t*)alloc((size_t)S_LEN * INNER * 2);
  bf16_t* VT   = (bf16_t*)alloc((size_t)S_LEN * INNER * 2);
  bf16_t* Pb   = (bf16_t*)alloc((size_t)NHEAD * S_LEN * S_LEN * 2);
  bf16_t* OUTb = (bf16_t*)alloc((size_t)S_LEN * INNER * 2);
  bf16_t* Wb   = (bf16_t*)alloc((size_t)UPCOLS * DMODEL * 2);
  bf16_t* Wb2  = (bf16_t*)alloc((size_t)DMODEL * INNER * 2);
  float*  IG   = (float*)alloc(NHEAD * S_LEN * 4);
  float*  FG   = (float*)alloc(NHEAD * S_LEN * 4);
  float*  AV   = (float*)alloc(NHEAD * S_LEN * 4);
  float*  PM   = (float*)alloc(NHEAD * S_LEN * 4);
  float*  NF   = (float*)alloc(NHEAD * S_LEN * 4);
  float*  NRAW = (float*)alloc(NHEAD * S_LEN * 4);
  float*  SCL  = (float*)alloc(NHEAD * S_LEN * 4);
  float* R1 = UP;   // final stage reuse (UP/XC dead by then)
  float* T1 = XC;
  float* latent_out = (float*)d_out;
  float* reward_out = (float*)d_out + (size_t)S_LEN * DMODEL;
  float* term_out   = reward_out + S_LEN;

  // Workspace guard: if the harness workspace is smaller than our footprint,
  // bail out cleanly (clean absmax failure) instead of corrupting device memory.
  if (off > ws_size) return;

  hipMemcpyAsync(X, tokens, (size_t)S_LEN * DMODEL * 4, hipMemcpyDeviceToDevice, stream);

  for (int l = 0; l < NLAYER; l++) {
    ln_kernel<<<S_LEN, 256, 0, stream>>>(X, ln_w + l * DMODEL, XN);
    cvt_f32_bf16<<<1024, 256, 0, stream>>>(up_w + (size_t)l * UPCOLS * DMODEL, Wb,
                                           UPCOLS * DMODEL / 4);
    gemm_kernel<0><<<dim3(UPCOLS / BN, S_LEN / BM, 1), 256, 0, stream>>>(
        XN, DMODEL, 0, Wb, DMODEL, 0, UP, UPCOLS, 0, nullptr, 0,
        S_LEN, UPCOLS, DMODEL, nullptr, nullptr, nullptr, nullptr, nullptr, 0, 0);
    conv_qkv_kernel<<<dim3(2, S_LEN), 256, 0, stream>>>(
        UP, conv_w + (size_t)l * INNER * 4, conv_b + l * INNER,
        q_w + (size_t)l * NBLK * 16, k_w + (size_t)l * NBLK * 16, v_w + (size_t)l * NBLK * 16,
        XC, Qb, Kb, Vb);
    transpose_bf16<<<dim3(64, 64), 256, 0, stream>>>(Vb, VT);
    gates_kernel<<<S_LEN, 256, 0, stream>>>(Qb, Kb, Vb, ig_w + (size_t)l * NHEAD * GIN,
                                            ig_b + l * NHEAD, fg_w + (size_t)l * NHEAD * GIN,
                                            fg_b + l * NHEAD, IG, FG);
    scan_kernel<<<NHEAD, 256, 0, stream>>>(IG, FG, AV, PM, NF);
    zero_f32<<<(NHEAD * S_LEN + 255) / 256, 256, 0, stream>>>(NRAW, NHEAD * S_LEN);
    gemm_kernel<3><<<dim3(S_LEN / BN, S_LEN / BM, NHEAD), 256, 0, stream>>>(
        Qb, INNER, DHEAD, Kb, INNER, DHEAD, nullptr, S_LEN, 0, Pb, (long long)S_LEN * S_LEN,
        S_LEN, S_LEN, DHEAD, nullptr, AV, PM, NRAW, nullptr, S_LEN, 0);
    scale_kernel<<<(NHEAD * S_LEN + 255) / 256, 256, 0, stream>>>(NRAW, NF, SCL, NHEAD * S_LEN);
    gemm_kernel<4><<<dim3(DHEAD / BN, S_LEN / BM, NHEAD), 256, 0, stream>>>(
        Pb, S_LEN, (long long)S_LEN * S_LEN, VT, S_LEN, (long long)DHEAD * S_LEN,
        Hbuf, INNER, DHEAD, nullptr, 0, S_LEN, DHEAD, S_LEN,
        nullptr, nullptr, nullptr, nullptr, SCL, S_LEN, 1);
    onorm_kernel<<<dim3(NHEAD, S_LEN), 256, 0, stream>>>(Hbuf, XC, UP, onormw + l * INNER,
                                                         skipw + l * INNER, OUTb);
    cvt_f32_bf16<<<1024, 256, 0, stream>>>(down_w + (size_t)l * DMODEL * INNER, Wb2,
                                           DMODEL * INNER / 4);
    gemm_kernel<1><<<dim3(DMODEL / BN, S_LEN / BM, 1), 256, 0, stream>>>(
        OUTb, INNER, 0, Wb2, INNER, 0, X, DMODEL, 0, nullptr, 0,
        S_LEN, DMODEL, INNER, nullptr, nullptr, nullptr, nullptr, nullptr, 0, 0);
  }

  // final heads
  ln_kernel<<<S_LEN, 256, 0, stream>>>(X, post_w, XN);
  bf16_t* Wlat = Wb;
  bf16_t* Wr1 = Wb + (size_t)DMODEL * DMODEL;
  bf16_t* Wt1 = Wb + 2 * (size_t)DMODEL * DMODEL;
  cvt_f32_bf16<<<512, 256, 0, stream>>>(lat_w, Wlat, DMODEL * DMODEL / 4);
  cvt_f32_bf16<<<512, 256, 0, stream>>>(r1_w, Wr1, DMODEL * DMODEL / 4);
  cvt_f32_bf16<<<512, 256, 0, stream>>>(t1_w, Wt1, DMODEL * DMODEL / 4);
  gemm_kernel<2><<<dim3(DMODEL / BN, S_LEN / BM, 1), 256, 0, stream>>>(
      XN, DMODEL, 0, Wlat, DMODEL, 0, latent_out, DMODEL, 0, nullptr, 0,
      S_LEN, DMODEL, DMODEL, lat_b, nullptr, nullptr, nullptr, nullptr, 0, 0);
  gemm_kernel<2><<<dim3(DMODEL / BN, S_LEN / BM, 1), 256, 0, stream>>>(
      XN, DMODEL, 0, Wr1, DMODEL, 0, R1, DMODEL, 0, nullptr, 0,
      S_LEN, DMODEL, DMODEL, r1_b, nullptr, nullptr, nullptr, nullptr, 0, 0);
  gemm_kernel<2><<<dim3(DMODEL / BN, S_LEN / BM, 1), 256, 0, stream>>>(
      XN, DMODEL, 0, Wt1, DMODEL, 0, T1, DMODEL, 0, nullptr, 0,
      S_LEN, DMODEL, DMODEL, t1_b, nullptr, nullptr, nullptr, nullptr, 0, 0);
  rt_kernel<<<S_LEN, 256, 0, stream>>>(R1, T1, r2_w, r2_b, t2_w, t2_b, reward_out, term_out);
}

// Round 3
// 1281.805 us; speedup vs baseline: 1.1030x; 1.1030x over previous
//
#include <hip/hip_runtime.h>
#include <hip/hip_bf16.h>
#include <math.h>
#include <cstdint>

typedef __bf16 bf16_t;
typedef bf16_t bf16x8 __attribute__((ext_vector_type(8)));
typedef bf16_t bf16x4 __attribute__((ext_vector_type(4)));
typedef bf16_t bf16x2 __attribute__((ext_vector_type(2)));
typedef float f32x4 __attribute__((ext_vector_type(4)));
typedef float f32x2 __attribute__((ext_vector_type(2)));

#define S_LEN 2048
#define DMODEL 1024
#define NLAYER 4
#define NHEAD 4
#define INNER 2048
#define DHEAD 512
#define NBLK 512
#define UPCOLS 4096
#define GIN 6144

// global -> LDS direct DMA, 16B per lane. Size must be a literal -> macro.
#define GLDS16(gp, lp)                                              \
  __builtin_amdgcn_global_load_lds(                                 \
      (const __attribute__((address_space(1))) void*)(gp),          \
      (__attribute__((address_space(3))) void*)(lp), 16, 0, 0)

// ---------------- zero f32 buffer ----------------
__global__ void zero_f32(float* __restrict__ p, int n) {
  int i = blockIdx.x * 256 + threadIdx.x;
  if (i < n) p[i] = 0.f;
}

// ---------------- convert f32 -> bf16 (vectorized, grid-stride) ----------------
__global__ __launch_bounds__(256) void cvt_f32_bf16(const float* __restrict__ in,
                                                    bf16_t* __restrict__ out, int n4) {
  int i = blockIdx.x * 256 + threadIdx.x;
  int stride = gridDim.x * 256;
  for (; i < n4; i += stride) {
    f32x4 v = ((const f32x4*)in)[i];
    bf16x4 o;
    #pragma unroll
    for (int j = 0; j < 4; j++) o[j] = (bf16_t)v[j];
    ((bf16x4*)out)[i] = o;
  }
}

// ---------------- LayerNorm (D=1024) -> bf16 ----------------
__global__ __launch_bounds__(256) void ln_kernel(const float* __restrict__ X,
                                                 const float* __restrict__ w,
                                                 bf16_t* __restrict__ out) {
  int s = blockIdx.x;
  int t = threadIdx.x;
  f32x4 v = ((const f32x4*)(X + (size_t)s * DMODEL))[t];
  float s1 = v[0] + v[1] + v[2] + v[3];
  float s2 = v[0]*v[0] + v[1]*v[1] + v[2]*v[2] + v[3]*v[3];
  __shared__ float b1[4], b2[4];
  #pragma unroll
  for (int off = 32; off; off >>= 1) { s1 += __shfl_xor(s1, off); s2 += __shfl_xor(s2, off); }
  if ((t & 63) == 0) { b1[t >> 6] = s1; b2[t >> 6] = s2; }
  __syncthreads();
  float tot1 = b1[0] + b1[1] + b1[2] + b1[3];
  float tot2 = b2[0] + b2[1] + b2[2] + b2[3];
  float mu = tot1 * (1.f / DMODEL);
  float var = tot2 * (1.f / DMODEL) - mu * mu;
  float rs = rsqrtf(var + 1e-5f);
  bf16x4 o;
  #pragma unroll
  for (int j = 0; j < 4; j++) o[j] = (bf16_t)((v[j] - mu) * rs * w[t * 4 + j]);
  ((bf16x4*)(out + (size_t)s * DMODEL))[t] = o;
}

// ---------------- causal conv(K=4)+silu + blockwise q/k/v ----------------
__global__ __launch_bounds__(256) void conv_qkv_kernel(
    const float* __restrict__ UP, const float* __restrict__ cw, const float* __restrict__ cb,
    const float* __restrict__ qw, const float* __restrict__ kw, const float* __restrict__ vw,
    float* __restrict__ XC, bf16_t* __restrict__ Q, bf16_t* __restrict__ Kb, bf16_t* __restrict__ V) {
  int s = blockIdx.y;
  int n = blockIdx.x * 256 + threadIdx.x;  // 0..511
  int c0 = n * 4;
  f32x4 zero4 = {};
  f32x4 xm[4];
  #pragma unroll
  for (int k = 0; k < 4; k++) {
    int sr = s + k - 3;
    xm[k] = (sr >= 0) ? *(const f32x4*)(UP + (size_t)sr * UPCOLS + c0) : zero4;
  }
  f32x4 cbv = *(const f32x4*)(cb + c0);
  float xc[4];
  #pragma unroll
  for (int d = 0; d < 4; d++) {
    f32x4 wv = *(const f32x4*)(cw + (size_t)(c0 + d) * 4);
    float a = cbv[d];
    #pragma unroll
    for (int k = 0; k < 4; k++) a += wv[k] * xm[k][d];
    xc[d] = a / (1.f + __expf(-a));  // silu
  }
  f32x4 xcv; xcv[0]=xc[0]; xcv[1]=xc[1]; xcv[2]=xc[2]; xcv[3]=xc[3];
  *(f32x4*)(XC + (size_t)s * INNER + c0) = xcv;
  bf16x4 qo, ko, vo;
  #pragma unroll
  for (int o = 0; o < 4; o++) {
    float aq = 0, ak = 0, av = 0;
    #pragma unroll
    for (int d = 0; d < 4; d++) {
      aq += qw[n * 16 + o * 4 + d] * xc[d];
      ak += kw[n * 16 + o * 4 + d] * xc[d];
      av += vw[n * 16 + o * 4 + d] * xm[3][d];  // v from pre-conv xm
    }
    qo[o] = (bf16_t)aq; ko[o] = (bf16_t)ak; vo[o] = (bf16_t)av;
  }
  ((bf16x4*)(Q  + (size_t)s * INNER))[n] = qo;
  ((bf16x4*)(Kb + (size_t)s * INNER))[n] = ko;
  ((bf16x4*)(V  + (size_t)s * INNER))[n] = vo;
}

// ---------------- bf16 transpose 2048x2048 ----------------
__global__ __launch_bounds__(256) void transpose_bf16(const bf16_t* __restrict__ in,
                                                      bf16_t* __restrict__ out) {
  __shared__ bf16_t tile[32][33];
  int c0 = blockIdx.x * 32, r0 = blockIdx.y * 32;
  int tx = threadIdx.x & 31, ty = threadIdx.x >> 5;
  #pragma unroll
  for (int i = ty; i < 32; i += 8) tile[i][tx] = in[(size_t)(r0 + i) * INNER + c0 + tx];
  __syncthreads();
  #pragma unroll
  for (int i = ty; i < 32; i += 8) out[(size_t)(c0 + i) * S_LEN + r0 + tx] = tile[tx][i];
}

// ---------------- input/forget gate logits ----------------
__global__ __launch_bounds__(256) void gates_kernel(
    const bf16_t* __restrict__ Q, const bf16_t* __restrict__ K, const bf16_t* __restrict__ V,
    const float* __restrict__ igw, const float* __restrict__ igb,
    const float* __restrict__ fgw, const float* __restrict__ fgb,
    float* __restrict__ IG, float* __restrict__ FG) {
  int s = blockIdx.x;
  float pi[NHEAD] = {0, 0, 0, 0}, pf[NHEAD] = {0, 0, 0, 0};
  for (int e = threadIdx.x; e < GIN; e += 256) {
    float g;
    if (e < INNER)            g = (float)Q[(size_t)s * INNER + e];
    else if (e < 2 * INNER)   g = (float)K[(size_t)s * INNER + e - INNER];
    else                      g = (float)V[(size_t)s * INNER + e - 2 * INNER];
    #pragma unroll
    for (int h = 0; h < NHEAD; h++) {
      pi[h] += g * igw[h * GIN + e];
      pf[h] += g * fgw[h * GIN + e];
    }
  }
  __shared__ float red[8][4];
  #pragma unroll
  for (int h = 0; h < NHEAD; h++) {
    float a = pi[h], b = pf[h];
    #pragma unroll
    for (int off = 32; off; off >>= 1) { a += __shfl_xor(a, off); b += __shfl_xor(b, off); }
    if ((threadIdx.x & 63) == 0) { red[h][threadIdx.x >> 6] = a; red[h + 4][threadIdx.x >> 6] = b; }
  }
  __syncthreads();
  if (threadIdx.x < NHEAD) {
    int h = threadIdx.x;
    IG[h * S_LEN + s] = red[h][0] + red[h][1] + red[h][2] + red[h][3] + igb[h];
    FG[h * S_LEN + s] = red[h + 4][0] + red[h + 4][1] + red[h + 4][2] + red[h + 4][3] + fgb[h];
  }
}

// ---------------- per-head scan: cs=cumsum(logsig(fg)), a=ig-cs, pm=prefmax(a), nf=exp(-(cs+pm)) ----
__global__ __launch_bounds__(256) void scan_kernel(const float* __restrict__ IG,
                                                   const float* __restrict__ FG,
                                                   float* __restrict__ AV, float* __restrict__ PM,
                                                   float* __restrict__ NF) {
  int h = blockIdx.x;
  int tid = threadIdx.x;
  const float* fg = FG + h * S_LEN;
  const float* ig = IG + h * S_LEN;
  float cs[8];
  float run = 0.f;
  #pragma unroll
  for (int i = 0; i < 8; i++) {
    float x = fg[tid * 8 + i];
    float l = (x >= 0.f) ? -log1pf(__expf(-x)) : (x - log1pf(__expf(x)));
    run += l; cs[i] = run;
  }
  __shared__ float sb[256];
  sb[tid] = run;
  __syncthreads();
  for (int off = 1; off < 256; off <<= 1) {
    float add = (tid >= off) ? sb[tid - off] : 0.f;
    __syncthreads();
    sb[tid] += add;
    __syncthreads();
  }
  float base = sb[tid] - run;  // exclusive prefix sum
  float a[8];
  float runm = -__builtin_inff();
  #pragma unroll
  for (int i = 0; i < 8; i++) {
    cs[i] += base;
    a[i] = ig[tid * 8 + i] - cs[i];
    runm = fmaxf(runm, a[i]);
  }
  __syncthreads();
  sb[tid] = runm;
  __syncthreads();
  for (int off = 1; off < 256; off <<= 1) {
    float other = (tid >= off) ? sb[tid - off] : -__builtin_inff();
    __syncthreads();
    sb[tid] = fmaxf(sb[tid], other);
    __syncthreads();
  }
  float rm = (tid == 0) ? -__builtin_inff() : sb[tid - 1];  // exclusive prefix max
  #pragma unroll
  for (int i = 0; i < 8; i++) {
    rm = fmaxf(rm, a[i]);
    AV[h * S_LEN + tid * 8 + i] = a[i];
    PM[h * S_LEN + tid * 8 + i] = rm;
    NF[h * S_LEN + tid * 8 + i] = __expf(-(cs[i] + rm));
  }
}

// ---------------- n = max(|nraw|, nf); scale = 1/(n+1e-6) ----------------
__global__ void scale_kernel(const float* __restrict__ nraw, const float* __restrict__ nf,
                             float* __restrict__ scale, int n) {
  int i = blockIdx.x * 256 + threadIdx.x;
  if (i < n) scale[i] = 1.f / (fmaxf(fabsf(nraw[i]), nf[i]) + 1e-6f);
}

// ---------------- per-head LN over DH + skip*xc, * silu(z) -> bf16 ----------------
__global__ __launch_bounds__(256) void onorm_kernel(
    const float* __restrict__ H, const float* __restrict__ XC, const float* __restrict__ UP,
    const float* __restrict__ onw, const float* __restrict__ skipw, bf16_t* __restrict__ OUT) {
  int h = blockIdx.x, s = blockIdx.y;
  int c = h * DHEAD + threadIdx.x * 2;
  f32x2 v = *(const f32x2*)(H + (size_t)s * INNER + c);
  float s1 = v[0] + v[1], s2 = v[0] * v[0] + v[1] * v[1];
  __shared__ float b1[4], b2[4];
  #pragma unroll
  for (int off = 32; off; off >>= 1) { s1 += __shfl_xor(s1, off); s2 += __shfl_xor(s2, off); }
  if ((threadIdx.x & 63) == 0) { b1[threadIdx.x >> 6] = s1; b2[threadIdx.x >> 6] = s2; }
  __syncthreads();
  float tot1 = b1[0] + b1[1] + b1[2] + b1[3];
  float tot2 = b2[0] + b2[1] + b2[2] + b2[3];
  float mu = tot1 * (1.f / DHEAD);
  float var = tot2 * (1.f / DHEAD) - mu * mu;
  float rs = rsqrtf(var + 1e-5f);
  bf16x2 o;
  #pragma unroll
  for (int j = 0; j < 2; j++) {
    float val = (v[j] - mu) * rs * onw[c + j] + skipw[c + j] * XC[(size_t)s * INNER + c + j];
    float z = UP[(size_t)s * UPCOLS + INNER + c + j];
    val *= z / (1.f + __expf(-z));
    o[j] = (bf16_t)val;
  }
  *(bf16x2*)(OUT + (size_t)s * INNER + c) = o;
}

// ---------------- latent slice copy + bias ----------------
__global__ __launch_bounds__(256) void latcopy_kernel(const float* __restrict__ Ch,
                                                      const float* __restrict__ b,
                                                      float* __restrict__ out) {
  int s = blockIdx.x, t = threadIdx.x;
  f32x4 v = ((const f32x4*)(Ch + (size_t)s * 3072))[t];
  f32x4 bb = ((const f32x4*)b)[t];
  f32x4 o; o[0]=v[0]+bb[0]; o[1]=v[1]+bb[1]; o[2]=v[2]+bb[2]; o[3]=v[3]+bb[3];
  ((f32x4*)(out + (size_t)s * DMODEL))[t] = o;
}

// ---------------- reward/term: row dot over D (reads merged head buffer) ----------------
__global__ __launch_bounds__(256) void rt_kernel(
    const float* __restrict__ Ch,
    const float* __restrict__ r1b, const float* __restrict__ t1b,
    const float* __restrict__ r2w, const float* __restrict__ r2b,
    const float* __restrict__ t2w, const float* __restrict__ t2b,
    float* __restrict__ outR, float* __restrict__ outT) {
  int s = blockIdx.x, t = threadIdx.x;
  f32x4 a = ((const f32x4*)(Ch + (size_t)s * 3072 + 1024))[t];
  f32x4 b = ((const f32x4*)(Ch + (size_t)s * 3072 + 2048))[t];
  f32x4 ab = ((const f32x4*)r1b)[t];
  f32x4 bb = ((const f32x4*)t1b)[t];
  f32x4 w1 = ((const f32x4*)r2w)[t];
  f32x4 w2 = ((const f32x4*)t2w)[t];
  float pr = 0, pt = 0;
  #pragma unroll
  for (int j = 0; j < 4; j++) {
    pr += (a[j] + ab[j]) * w1[j];
    pt += (b[j] + bb[j]) * w2[j];
  }
  __shared__ float rb[4], tb[4];
  #pragma unroll
  for (int off = 32; off; off >>= 1) { pr += __shfl_xor(pr, off); pt += __shfl_xor(pt, off); }
  if ((t & 63) == 0) { rb[t >> 6] = pr; tb[t >> 6] = pt; }
  __syncthreads();
  if (t == 0) {
    outR[s] = rb[0] + rb[1] + rb[2] + rb[3] + r2b[0];
    outT[s] = tb[0] + tb[1] + tb[2] + tb[3] + t2b[0];
  }
}

// ================= bf16 MFMA NT GEMM, 128x128 tile, BK=32, 4 waves =================
// m97 structure: global_load_lds width-16 staging, linear LDS, XOR-swizzled
// chunk placement (pre-swizzled global source + swizzled ds_read -> 2-way banks).
// MODE 0: C = A*B^T    MODE 1: C += A*B^T
// MODE 3: decay epilogue -> P bf16 (LDS-bounced coalesced store) + row-sum atomics
// MODE 4: C = (A*B^T) * scale[row]  with causal K-limit  (PV)
#define BM 128
#define BN 128
#define BKK 32

template <int MODE>
__global__ __launch_bounds__(256) void gemm_kernel(
    const bf16_t* __restrict__ A, int lda, long long sAz,
    const bf16_t* __restrict__ B, int ldb, long long sBz,
    float* __restrict__ C, int ldc, long long sCz,
    bf16_t* __restrict__ P, long long sPz,
    int M, int N, int K,
    const float* __restrict__ avec, const float* __restrict__ pmvec,
    float* __restrict__ nraw,
    const float* __restrict__ scalev, long long sVz, int causal) {
  int z = blockIdx.z;
  int m0 = blockIdx.y * BM;
  int n0 = blockIdx.x * BN;
  if (MODE == 3 && n0 > m0 + (BM - 1)) return;  // fully-masked causal tile
  A += z * sAz; B += z * sBz;
  int Keff = K;
  if (MODE == 4 && causal) { int ke = m0 + BM; Keff = ke < K ? ke : K; }

  // LDS: stage A[128][32]+B[128][32] bf16 (16KB); MODE 3 reuses as P bounce [128][136]
  constexpr int STAGE_E = (BM + BN) * BKK;
  constexpr int SME = (MODE == 3) ? (128 * 136) : STAGE_E;
  __shared__ __align__(16) bf16_t smem[SME];
  bf16_t* As = smem;
  bf16_t* Bs = smem + BM * BKK;

  int tid = threadIdx.x;
  int lane = tid & 63;
  int wave = tid >> 6;
  int wr = wave >> 1, wc = wave & 1;
  int l15 = lane & 15, lk = lane >> 4;

  // ---- staging addresses: wave w covers LDS rows w*32..w*32+31 (2 issues) ----
  // LDS slot (row, c') holds global chunk c = c' ^ ((row>>1)&3); DMA writes
  // linearly (lane*16), so the swizzle is applied to the GLOBAL source address.
  int srow = wave * 32 + (lane >> 2);
  int cchunk = ((lane & 3) ^ ((lane >> 3) & 3)) * 8;  // element offset in row
  const bf16_t* gA = A + (size_t)(m0 + srow) * lda + cchunk;
  const bf16_t* gB = B + (size_t)(n0 + srow) * ldb + cchunk;
  bf16_t* ldsA = As + wave * 1024;  // elements; +512 = 16 rows later
  bf16_t* ldsB = Bs + wave * 1024;
  size_t a16 = (size_t)16 * lda, b16 = (size_t)16 * ldb;

  // ---- fragment read byte-offsets (swizzled to match) ----
  int aoff[4], boff[4];
  #pragma unroll
  for (int m = 0; m < 4; m++) {
    int ra = wr * 64 + m * 16 + l15;
    aoff[m] = ra * 64 + (lk ^ ((ra >> 1) & 3)) * 16;
    int rb = wc * 64 + m * 16 + l15;
    boff[m] = rb * 64 + (lk ^ ((rb >> 1) & 3)) * 16;
  }

  f32x4 acc[4][4] = {};

  for (int k0 = 0; k0 < Keff; k0 += BKK) {
    GLDS16(gA + k0, ldsA);
    GLDS16(gA + k0 + a16, ldsA + 512);
    GLDS16(gB + k0, ldsB);
    GLDS16(gB + k0 + b16, ldsB + 512);
    __syncthreads();  // drains vmcnt (DMA) before anyone reads
    bf16x8 af[4], bfv[4];
    #pragma unroll
    for (int m = 0; m < 4; m++) af[m] = *(const bf16x8*)((const char*)As + aoff[m]);
    #pragma unroll
    for (int n = 0; n < 4; n++) bfv[n] = *(const bf16x8*)((const char*)Bs + boff[n]);
    #pragma unroll
    for (int m = 0; m < 4; m++)
      #pragma unroll
      for (int n = 0; n < 4; n++)
        acc[m][n] = __builtin_amdgcn_mfma_f32_16x16x32_bf16(af[m], bfv[n], acc[m][n], 0, 0, 0);
    __syncthreads();  // all reads done before next iter's DMA overwrites
  }

  int rbase = m0 + wr * 64;
  int cbase = n0 + wc * 64;
  if (MODE == 3) {
    const float* av = avec + z * sVz;
    const float* pv = pmvec + z * sVz;
    float* nr = nraw + z * sVz;
    bf16_t* Pp = P + z * sPz;
    const float ISQ = 0.04419417382415922f;  // 1/sqrt(512)
    #pragma unroll
    for (int m = 0; m < 4; m++) {
      float rsum[4] = {0, 0, 0, 0};
      #pragma unroll
      for (int n = 0; n < 4; n++) {
        int cg = cbase + n * 16 + l15;
        float aexp = av[cg];
        #pragma unroll
        for (int r = 0; r < 4; r++) {
          int rg = rbase + m * 16 + lk * 4 + r;
          float val = 0.f;
          if (cg <= rg) val = acc[m][n][r] * ISQ * __expf(aexp - pv[rg]);
          smem[(size_t)(wr * 64 + m * 16 + lk * 4 + r) * 136 + wc * 64 + n * 16 + l15] =
              (bf16_t)val;
          rsum[r] += val;
        }
      }
      #pragma unroll
      for (int r = 0; r < 4; r++) {
        float v = rsum[r];
        v += __shfl_xor(v, 1); v += __shfl_xor(v, 2); v += __shfl_xor(v, 4); v += __shfl_xor(v, 8);
        if (l15 == 0) atomicAdd(&nr[rbase + m * 16 + lk * 4 + r], v);
      }
    }
    __syncthreads();
    // coalesced bf16x8 stores of the bounced tile
    #pragma unroll
    for (int i = 0; i < 8; i++) {
      int chunk = tid + i * 256;          // 0..2047
      int row = chunk >> 4, cc = chunk & 15;
      *(bf16x8*)(Pp + (size_t)(m0 + row) * ldc + n0 + cc * 8) =
          *(const bf16x8*)(smem + (size_t)row * 136 + cc * 8);
    }
  } else {
    #pragma unroll
    for (int m = 0; m < 4; m++) {
      #pragma unroll
      for (int r = 0; r < 4; r++) {
        int rg = rbase + m * 16 + lk * 4 + r;
        float rowscale = (MODE == 4) ? scalev[z * sVz + rg] : 1.f;
        #pragma unroll
        for (int n = 0; n < 4; n++) {
          int cg = cbase + n * 16 + l15;
          size_t idx = (size_t)z * sCz + (size_t)rg * ldc + cg;
          float v = acc[m][n][r];
          if (MODE == 1) C[idx] += v;
          else if (MODE == 4) C[idx] = v * rowscale;
          else C[idx] = v;
        }
      }
    }
  }
}

extern "C" void kernel_launch(void* const* d_in, const int* in_sizes, int n_in,
                              void* d_out, int out_size, void* d_ws, size_t ws_size,
                              hipStream_t stream) {
  const float* tokens = (const float*)d_in[0];
  const float* ln_w   = (const float*)d_in[1];
  const float* up_w   = (const float*)d_in[2];
  const float* conv_w = (const float*)d_in[3];
  const float* conv_b = (const float*)d_in[4];
  const float* q_w    = (const float*)d_in[5];
  const float* k_w    = (const float*)d_in[6];
  const float* v_w    = (const float*)d_in[7];
  const float* ig_w   = (const float*)d_in[8];
  const float* ig_b   = (const float*)d_in[9];
  const float* fg_w   = (const float*)d_in[10];
  const float* fg_b   = (const float*)d_in[11];
  const float* skipw  = (const float*)d_in[12];
  const float* onormw = (const float*)d_in[13];
  const float* down_w = (const float*)d_in[14];
  const float* post_w = (const float*)d_in[15];
  const float* lat_w  = (const float*)d_in[16];
  const float* lat_b  = (const float*)d_in[17];
  const float* r1_w   = (const float*)d_in[18];
  const float* r1_b   = (const float*)d_in[19];
  const float* r2_w   = (const float*)d_in[20];
  const float* r2_b   = (const float*)d_in[21];
  const float* t1_w   = (const float*)d_in[22];
  const float* t1_b   = (const float*)d_in[23];
  const float* t2_w   = (const float*)d_in[24];
  const float* t2_b   = (const float*)d_in[25];

  char* ws = (char*)d_ws;
  size_t off = 0;
  auto alloc = [&](size_t bytes) -> char* {
    char* p = ws + off;
    off += (bytes + 255) & ~(size_t)255;
    return p;
  };
  float*  X    = (float*)alloc((size_t)S_LEN * DMODEL * 4);
  float*  UP   = (float*)alloc((size_t)S_LEN * UPCOLS * 4);   // reused as Chead at end
  float*  XC   = (float*)alloc((size_t)S_LEN * INNER * 4);
  float*  Hbuf = (float*)alloc((size_t)S_LEN * INNER * 4);
  bf16_t* XN   = (bf16_t*)alloc((size_t)S_LEN * DMODEL * 2);
  bf16_t* Qb   = (bf16_t*)alloc((size_t)S_LEN * INNER * 2);
  bf16_t* Kb   = (bf16_t*)alloc((size_t)S_LEN * INNER * 2);
  bf16_t* Vb   = (bf16_t*)alloc((size_t)S_LEN * INNER * 2);
  bf16_t* VT   = (bf16_t*)alloc((size_t)S_LEN * INNER * 2);
  bf16_t* Pb   = (bf16_t*)alloc((size_t)NHEAD * S_LEN * S_LEN * 2);
  bf16_t* OUTb = (bf16_t*)alloc((size_t)S_LEN * INNER * 2);
  bf16_t* Wb   = (bf16_t*)alloc((size_t)UPCOLS * DMODEL * 2);
  bf16_t* Wb2  = (bf16_t*)alloc((size_t)DMODEL * INNER * 2);
  float*  IG   = (float*)alloc(NHEAD * S_LEN * 4);
  float*  FG   = (float*)alloc(NHEAD * S_LEN * 4);
  float*  AV   = (float*)alloc(NHEAD * S_LEN * 4);
  float*  PM   = (float*)alloc(NHEAD * S_LEN * 4);
  float*  NF   = (float*)alloc(NHEAD * S_LEN * 4);
  float*  NRAW = (float*)alloc(NHEAD * S_LEN * 4);
  float*  SCL  = (float*)alloc(NHEAD * S_LEN * 4);
  float* Chead = UP;  // [2048][3072] f32 (24MB <= UP's 32MB), UP dead by then
  float* latent_out = (float*)d_out;
  float* reward_out = (float*)d_out + (size_t)S_LEN * DMODEL;
  float* term_out   = reward_out + S_LEN;

  if (off > ws_size) return;  // clean failure instead of OOB corruption

  hipMemcpyAsync(X, tokens, (size_t)S_LEN * DMODEL * 4, hipMemcpyDeviceToDevice, stream);

  for (int l = 0; l < NLAYER; l++) {
    ln_kernel<<<S_LEN, 256, 0, stream>>>(X, ln_w + l * DMODEL, XN);
    cvt_f32_bf16<<<1024, 256, 0, stream>>>(up_w + (size_t)l * UPCOLS * DMODEL, Wb,
                                           UPCOLS * DMODEL / 4);
    gemm_kernel<0><<<dim3(UPCOLS / BN, S_LEN / BM, 1), 256, 0, stream>>>(
        XN, DMODEL, 0, Wb, DMODEL, 0, UP, UPCOLS, 0, nullptr, 0,
        S_LEN, UPCOLS, DMODEL, nullptr, nullptr, nullptr, nullptr, 0, 0);
    conv_qkv_kernel<<<dim3(2, S_LEN), 256, 0, stream>>>(
        UP, conv_w + (size_t)l * INNER * 4, conv_b + l * INNER,
        q_w + (size_t)l * NBLK * 16, k_w + (size_t)l * NBLK * 16, v_w + (size_t)l * NBLK * 16,
        XC, Qb, Kb, Vb);
    transpose_bf16<<<dim3(64, 64), 256, 0, stream>>>(Vb, VT);
    gates_kernel<<<S_LEN, 256, 0, stream>>>(Qb, Kb, Vb, ig_w + (size_t)l * NHEAD * GIN,
                                            ig_b + l * NHEAD, fg_w + (size_t)l * NHEAD * GIN,
                                            fg_b + l * NHEAD, IG, FG);
    scan_kernel<<<NHEAD, 256, 0, stream>>>(IG, FG, AV, PM, NF);
    zero_f32<<<(NHEAD * S_LEN + 255) / 256, 256, 0, stream>>>(NRAW, NHEAD * S_LEN);
    gemm_kernel<3><<<dim3(S_LEN / BN, S_LEN / BM, NHEAD), 256, 0, stream>>>(
        Qb, INNER, DHEAD, Kb, INNER, DHEAD, nullptr, S_LEN, 0, Pb, (long long)S_LEN * S_LEN,
        S_LEN, S_LEN, DHEAD, AV, PM, NRAW, nullptr, S_LEN, 0);
    scale_kernel<<<(NHEAD * S_LEN + 255) / 256, 256, 0, stream>>>(NRAW, NF, SCL, NHEAD * S_LEN);
    gemm_kernel<4><<<dim3(DHEAD / BN, S_LEN / BM, NHEAD), 256, 0, stream>>>(
        Pb, S_LEN, (long long)S_LEN * S_LEN, VT, S_LEN, (long long)DHEAD * S_LEN,
        Hbuf, INNER, DHEAD, nullptr, 0, S_LEN, DHEAD, S_LEN,
        nullptr, nullptr, nullptr, SCL, S_LEN, 1);
    onorm_kernel<<<dim3(NHEAD, S_LEN), 256, 0, stream>>>(Hbuf, XC, UP, onormw + l * INNER,
                                                         skipw + l * INNER, OUTb);
    cvt_f32_bf16<<<1024, 256, 0, stream>>>(down_w + (size_t)l * DMODEL * INNER, Wb2,
                                           DMODEL * INNER / 4);
    gemm_kernel<1><<<dim3(DMODEL / BN, S_LEN / BM, 1), 256, 0, stream>>>(
        OUTb, INNER, 0, Wb2, INNER, 0, X, DMODEL, 0, nullptr, 0,
        S_LEN, DMODEL, INNER, nullptr, nullptr, nullptr, nullptr, 0, 0);
  }

  // final heads: one merged GEMM over [lat | r1 | t1]  (N = 3072)
  ln_kernel<<<S_LEN, 256, 0, stream>>>(X, post_w, XN);
  bf16_t* Wh = Wb;  // [3072][1024] bf16
  cvt_f32_bf16<<<512, 256, 0, stream>>>(lat_w, Wh, DMODEL * DMODEL / 4);
  cvt_f32_bf16<<<512, 256, 0, stream>>>(r1_w, Wh + (size_t)DMODEL * DMODEL, DMODEL * DMODEL / 4);
  cvt_f32_bf16<<<512, 256, 0, stream>>>(t1_w, Wh + 2 * (size_t)DMODEL * DMODEL,
                                        DMODEL * DMODEL / 4);
  gemm_kernel<0><<<dim3(3072 / BN, S_LEN / BM, 1), 256, 0, stream>>>(
      XN, DMODEL, 0, Wh, DMODEL, 0, Chead, 3072, 0, nullptr, 0,
      S_LEN, 3072, DMODEL, nullptr, nullptr, nullptr, nullptr, 0, 0);
  latcopy_kernel<<<S_LEN, 256, 0, stream>>>(Chead, lat_b, latent_out);
  rt_kernel<<<S_LEN, 256, 0, stream>>>(Chead, r1_b, t1_b, r2_w, r2_b, t2_w, t2_b,
                                       reward_out, term_out);
}

// Round 4
// 1049.456 us; speedup vs baseline: 1.3472x; 1.2214x over previous
//
#include <hip/hip_runtime.h>
#include <hip/hip_bf16.h>
#include <math.h>
#include <cstdint>

typedef __bf16 bf16_t;
typedef bf16_t bf16x8 __attribute__((ext_vector_type(8)));
typedef bf16_t bf16x4 __attribute__((ext_vector_type(4)));
typedef bf16_t bf16x2 __attribute__((ext_vector_type(2)));
typedef float f32x4 __attribute__((ext_vector_type(4)));
typedef float f32x2 __attribute__((ext_vector_type(2)));

#define S_LEN 2048
#define DMODEL 1024
#define NLAYER 4
#define NHEAD 4
#define INNER 2048
#define DHEAD 512
#define NBLK 512
#define UPCOLS 4096
#define GIN 6144

// global -> LDS direct DMA, 16B per lane. Size must be a literal -> macro.
#define GLDS16(gp, lp)                                              \
  __builtin_amdgcn_global_load_lds(                                 \
      (const __attribute__((address_space(1))) void*)(gp),          \
      (__attribute__((address_space(3))) void*)(lp), 16, 0, 0)

// ---------------- zero f32 buffers ----------------
__global__ void zero_f32(float* __restrict__ p, int n) {
  int i = blockIdx.x * 256 + threadIdx.x;
  if (i < n) p[i] = 0.f;
}
__global__ __launch_bounds__(256) void zero4_f32(float* __restrict__ p, int n4) {
  int i = blockIdx.x * 256 + threadIdx.x;
  int stride = gridDim.x * 256;
  f32x4 z = {};
  for (; i < n4; i += stride) ((f32x4*)p)[i] = z;
}

// ---------------- convert f32 -> bf16 (vectorized, grid-stride) ----------------
__global__ __launch_bounds__(256) void cvt_f32_bf16(const float* __restrict__ in,
                                                    bf16_t* __restrict__ out, int n4) {
  int i = blockIdx.x * 256 + threadIdx.x;
  int stride = gridDim.x * 256;
  for (; i < n4; i += stride) {
    f32x4 v = ((const f32x4*)in)[i];
    bf16x4 o;
    #pragma unroll
    for (int j = 0; j < 4; j++) o[j] = (bf16_t)v[j];
    ((bf16x4*)out)[i] = o;
  }
}

// ---------------- LayerNorm (D=1024) -> bf16 ----------------
__global__ __launch_bounds__(256) void ln_kernel(const float* __restrict__ X,
                                                 const float* __restrict__ w,
                                                 bf16_t* __restrict__ out) {
  int s = blockIdx.x;
  int t = threadIdx.x;
  f32x4 v = ((const f32x4*)(X + (size_t)s * DMODEL))[t];
  float s1 = v[0] + v[1] + v[2] + v[3];
  float s2 = v[0]*v[0] + v[1]*v[1] + v[2]*v[2] + v[3]*v[3];
  __shared__ float b1[4], b2[4];
  #pragma unroll
  for (int off = 32; off; off >>= 1) { s1 += __shfl_xor(s1, off); s2 += __shfl_xor(s2, off); }
  if ((t & 63) == 0) { b1[t >> 6] = s1; b2[t >> 6] = s2; }
  __syncthreads();
  float tot1 = b1[0] + b1[1] + b1[2] + b1[3];
  float tot2 = b2[0] + b2[1] + b2[2] + b2[3];
  float mu = tot1 * (1.f / DMODEL);
  float var = tot2 * (1.f / DMODEL) - mu * mu;
  float rs = rsqrtf(var + 1e-5f);
  bf16x4 o;
  #pragma unroll
  for (int j = 0; j < 4; j++) o[j] = (bf16_t)((v[j] - mu) * rs * w[t * 4 + j]);
  ((bf16x4*)(out + (size_t)s * DMODEL))[t] = o;
}

// ---------------- causal conv(K=4)+silu + blockwise q/k/v ----------------
__global__ __launch_bounds__(256) void conv_qkv_kernel(
    const float* __restrict__ UP, const float* __restrict__ cw, const float* __restrict__ cb,
    const float* __restrict__ qw, const float* __restrict__ kw, const float* __restrict__ vw,
    float* __restrict__ XC, bf16_t* __restrict__ Q, bf16_t* __restrict__ Kb, bf16_t* __restrict__ V) {
  int s = blockIdx.y;
  int n = blockIdx.x * 256 + threadIdx.x;  // 0..511
  int c0 = n * 4;
  f32x4 zero4 = {};
  f32x4 xm[4];
  #pragma unroll
  for (int k = 0; k < 4; k++) {
    int sr = s + k - 3;
    xm[k] = (sr >= 0) ? *(const f32x4*)(UP + (size_t)sr * UPCOLS + c0) : zero4;
  }
  f32x4 cbv = *(const f32x4*)(cb + c0);
  float xc[4];
  #pragma unroll
  for (int d = 0; d < 4; d++) {
    f32x4 wv = *(const f32x4*)(cw + (size_t)(c0 + d) * 4);
    float a = cbv[d];
    #pragma unroll
    for (int k = 0; k < 4; k++) a += wv[k] * xm[k][d];
    xc[d] = a / (1.f + __expf(-a));  // silu
  }
  f32x4 xcv; xcv[0]=xc[0]; xcv[1]=xc[1]; xcv[2]=xc[2]; xcv[3]=xc[3];
  *(f32x4*)(XC + (size_t)s * INNER + c0) = xcv;
  bf16x4 qo, ko, vo;
  #pragma unroll
  for (int o = 0; o < 4; o++) {
    float aq = 0, ak = 0, av = 0;
    #pragma unroll
    for (int d = 0; d < 4; d++) {
      aq += qw[n * 16 + o * 4 + d] * xc[d];
      ak += kw[n * 16 + o * 4 + d] * xc[d];
      av += vw[n * 16 + o * 4 + d] * xm[3][d];  // v from pre-conv xm
    }
    qo[o] = (bf16_t)aq; ko[o] = (bf16_t)ak; vo[o] = (bf16_t)av;
  }
  ((bf16x4*)(Q  + (size_t)s * INNER))[n] = qo;
  ((bf16x4*)(Kb + (size_t)s * INNER))[n] = ko;
  ((bf16x4*)(V  + (size_t)s * INNER))[n] = vo;
}

// ---------------- bf16 transpose 2048x2048 ----------------
__global__ __launch_bounds__(256) void transpose_bf16(const bf16_t* __restrict__ in,
                                                      bf16_t* __restrict__ out) {
  __shared__ bf16_t tile[32][33];
  int c0 = blockIdx.x * 32, r0 = blockIdx.y * 32;
  int tx = threadIdx.x & 31, ty = threadIdx.x >> 5;
  #pragma unroll
  for (int i = ty; i < 32; i += 8) tile[i][tx] = in[(size_t)(r0 + i) * INNER + c0 + tx];
  __syncthreads();
  #pragma unroll
  for (int i = ty; i < 32; i += 8) out[(size_t)(c0 + i) * S_LEN + r0 + tx] = tile[tx][i];
}

// ---------------- input/forget gate logits ----------------
__global__ __launch_bounds__(256) void gates_kernel(
    const bf16_t* __restrict__ Q, const bf16_t* __restrict__ K, const bf16_t* __restrict__ V,
    const float* __restrict__ igw, const float* __restrict__ igb,
    const float* __restrict__ fgw, const float* __restrict__ fgb,
    float* __restrict__ IG, float* __restrict__ FG) {
  int s = blockIdx.x;
  float pi[NHEAD] = {0, 0, 0, 0}, pf[NHEAD] = {0, 0, 0, 0};
  for (int e = threadIdx.x; e < GIN; e += 256) {
    float g;
    if (e < INNER)            g = (float)Q[(size_t)s * INNER + e];
    else if (e < 2 * INNER)   g = (float)K[(size_t)s * INNER + e - INNER];
    else                      g = (float)V[(size_t)s * INNER + e - 2 * INNER];
    #pragma unroll
    for (int h = 0; h < NHEAD; h++) {
      pi[h] += g * igw[h * GIN + e];
      pf[h] += g * fgw[h * GIN + e];
    }
  }
  __shared__ float red[8][4];
  #pragma unroll
  for (int h = 0; h < NHEAD; h++) {
    float a = pi[h], b = pf[h];
    #pragma unroll
    for (int off = 32; off; off >>= 1) { a += __shfl_xor(a, off); b += __shfl_xor(b, off); }
    if ((threadIdx.x & 63) == 0) { red[h][threadIdx.x >> 6] = a; red[h + 4][threadIdx.x >> 6] = b; }
  }
  __syncthreads();
  if (threadIdx.x < NHEAD) {
    int h = threadIdx.x;
    IG[h * S_LEN + s] = red[h][0] + red[h][1] + red[h][2] + red[h][3] + igb[h];
    FG[h * S_LEN + s] = red[h + 4][0] + red[h + 4][1] + red[h + 4][2] + red[h + 4][3] + fgb[h];
  }
}

// ---------------- per-head scan: cs=cumsum(logsig(fg)), a=ig-cs, pm=prefmax(a), nf=exp(-(cs+pm)) ----
__global__ __launch_bounds__(256) void scan_kernel(const float* __restrict__ IG,
                                                   const float* __restrict__ FG,
                                                   float* __restrict__ AV, float* __restrict__ PM,
                                                   float* __restrict__ NF) {
  int h = blockIdx.x;
  int tid = threadIdx.x;
  const float* fg = FG + h * S_LEN;
  const float* ig = IG + h * S_LEN;
  float cs[8];
  float run = 0.f;
  #pragma unroll
  for (int i = 0; i < 8; i++) {
    float x = fg[tid * 8 + i];
    float l = (x >= 0.f) ? -log1pf(__expf(-x)) : (x - log1pf(__expf(x)));
    run += l; cs[i] = run;
  }
  __shared__ float sb[256];
  sb[tid] = run;
  __syncthreads();
  for (int off = 1; off < 256; off <<= 1) {
    float add = (tid >= off) ? sb[tid - off] : 0.f;
    __syncthreads();
    sb[tid] += add;
    __syncthreads();
  }
  float base = sb[tid] - run;  // exclusive prefix sum
  float a[8];
  float runm = -__builtin_inff();
  #pragma unroll
  for (int i = 0; i < 8; i++) {
    cs[i] += base;
    a[i] = ig[tid * 8 + i] - cs[i];
    runm = fmaxf(runm, a[i]);
  }
  __syncthreads();
  sb[tid] = runm;
  __syncthreads();
  for (int off = 1; off < 256; off <<= 1) {
    float other = (tid >= off) ? sb[tid - off] : -__builtin_inff();
    __syncthreads();
    sb[tid] = fmaxf(sb[tid], other);
    __syncthreads();
  }
  float rm = (tid == 0) ? -__builtin_inff() : sb[tid - 1];  // exclusive prefix max
  #pragma unroll
  for (int i = 0; i < 8; i++) {
    rm = fmaxf(rm, a[i]);
    AV[h * S_LEN + tid * 8 + i] = a[i];
    PM[h * S_LEN + tid * 8 + i] = rm;
    NF[h * S_LEN + tid * 8 + i] = __expf(-(cs[i] + rm));
  }
}

// ---------------- n = max(|nraw|, nf); scale = 1/(n+1e-6) ----------------
__global__ void scale_kernel(const float* __restrict__ nraw, const float* __restrict__ nf,
                             float* __restrict__ scale, int n) {
  int i = blockIdx.x * 256 + threadIdx.x;
  if (i < n) scale[i] = 1.f / (fmaxf(fabsf(nraw[i]), nf[i]) + 1e-6f);
}

// ---------------- per-head LN over DH + skip*xc, * silu(z) -> bf16 ----------------
__global__ __launch_bounds__(256) void onorm_kernel(
    const float* __restrict__ H, const float* __restrict__ XC, const float* __restrict__ UP,
    const float* __restrict__ onw, const float* __restrict__ skipw, bf16_t* __restrict__ OUT) {
  int h = blockIdx.x, s = blockIdx.y;
  int c = h * DHEAD + threadIdx.x * 2;
  f32x2 v = *(const f32x2*)(H + (size_t)s * INNER + c);
  float s1 = v[0] + v[1], s2 = v[0] * v[0] + v[1] * v[1];
  __shared__ float b1[4], b2[4];
  #pragma unroll
  for (int off = 32; off; off >>= 1) { s1 += __shfl_xor(s1, off); s2 += __shfl_xor(s2, off); }
  if ((threadIdx.x & 63) == 0) { b1[threadIdx.x >> 6] = s1; b2[threadIdx.x >> 6] = s2; }
  __syncthreads();
  float tot1 = b1[0] + b1[1] + b1[2] + b1[3];
  float tot2 = b2[0] + b2[1] + b2[2] + b2[3];
  float mu = tot1 * (1.f / DHEAD);
  float var = tot2 * (1.f / DHEAD) - mu * mu;
  float rs = rsqrtf(var + 1e-5f);
  bf16x2 o;
  #pragma unroll
  for (int j = 0; j < 2; j++) {
    float val = (v[j] - mu) * rs * onw[c + j] + skipw[c + j] * XC[(size_t)s * INNER + c + j];
    float z = UP[(size_t)s * UPCOLS + INNER + c + j];
    val *= z / (1.f + __expf(-z));
    o[j] = (bf16_t)val;
  }
  *(bf16x2*)(OUT + (size_t)s * INNER + c) = o;
}

// ---------------- latent slice copy + bias ----------------
__global__ __launch_bounds__(256) void latcopy_kernel(const float* __restrict__ Ch,
                                                      const float* __restrict__ b,
                                                      float* __restrict__ out) {
  int s = blockIdx.x, t = threadIdx.x;
  f32x4 v = ((const f32x4*)(Ch + (size_t)s * 3072))[t];
  f32x4 bb = ((const f32x4*)b)[t];
  f32x4 o; o[0]=v[0]+bb[0]; o[1]=v[1]+bb[1]; o[2]=v[2]+bb[2]; o[3]=v[3]+bb[3];
  ((f32x4*)(out + (size_t)s * DMODEL))[t] = o;
}

// ---------------- reward/term: row dot over D (reads merged head buffer) ----------------
__global__ __launch_bounds__(256) void rt_kernel(
    const float* __restrict__ Ch,
    const float* __restrict__ r1b, const float* __restrict__ t1b,
    const float* __restrict__ r2w, const float* __restrict__ r2b,
    const float* __restrict__ t2w, const float* __restrict__ t2b,
    float* __restrict__ outR, float* __restrict__ outT) {
  int s = blockIdx.x, t = threadIdx.x;
  f32x4 a = ((const f32x4*)(Ch + (size_t)s * 3072 + 1024))[t];
  f32x4 b = ((const f32x4*)(Ch + (size_t)s * 3072 + 2048))[t];
  f32x4 ab = ((const f32x4*)r1b)[t];
  f32x4 bb = ((const f32x4*)t1b)[t];
  f32x4 w1 = ((const f32x4*)r2w)[t];
  f32x4 w2 = ((const f32x4*)t2w)[t];
  float pr = 0, pt = 0;
  #pragma unroll
  for (int j = 0; j < 4; j++) {
    pr += (a[j] + ab[j]) * w1[j];
    pt += (b[j] + bb[j]) * w2[j];
  }
  __shared__ float rb[4], tb[4];
  #pragma unroll
  for (int off = 32; off; off >>= 1) { pr += __shfl_xor(pr, off); pt += __shfl_xor(pt, off); }
  if ((t & 63) == 0) { rb[t >> 6] = pr; tb[t >> 6] = pt; }
  __syncthreads();
  if (t == 0) {
    outR[s] = rb[0] + rb[1] + rb[2] + rb[3] + r2b[0];
    outT[s] = tb[0] + tb[1] + tb[2] + tb[3] + t2b[0];
  }
}

// ================= bf16 MFMA NT GEMM, 128x128 tile, BK=64, double-buffered =================
// Pipeline (T3+T4 minimum form): stage(t+1) -> s_waitcnt vmcnt(8) -> s_barrier ->
// ds_read+MFMA -> s_barrier. Counted vmcnt keeps next tile's 8 DMAs/wave in flight
// across the barrier (never drains to 0 mid-loop).
// LDS swizzle: linear dest (global_load_lds requirement), chunk c' holds global
// chunk c'^ (row&7); read side applies the same XOR (both-sides rule #21).
// MODE 0: C = A*B^T              MODE 3: decay epilogue -> P bf16 + row-sum atomics
// MODE 4: atomicAdd C += (A*B^T)*scale[row], causal split-K over z (2 per head)
// MODE 5: atomicAdd C += A*B^T, split-K over z
#define BM 128
#define BN 128
#define BKK 64

template <int MODE>
__global__ __launch_bounds__(256) void gemm_kernel(
    const bf16_t* __restrict__ A, int lda, long long sAz,
    const bf16_t* __restrict__ B, int ldb, long long sBz,
    float* __restrict__ C, int ldc, long long sCz,
    bf16_t* __restrict__ P, long long sPz,
    int K,
    const float* __restrict__ avec, const float* __restrict__ pmvec,
    float* __restrict__ nraw,
    const float* __restrict__ scalev, long long sVz) {
  // ---- bijective XCD swizzle (m204): consecutive logical tiles share an XCD's L2 ----
  int gx = gridDim.x, gxy = gx * gridDim.y;
  int nwg = gxy * gridDim.z;
  int orig = blockIdx.z * gxy + blockIdx.y * gx + blockIdx.x;
  int xcd = orig & 7, lo = orig >> 3;
  int q8 = nwg >> 3, r8 = nwg & 7;
  int wg = (xcd < r8 ? xcd * (q8 + 1) : r8 * (q8 + 1) + (xcd - r8) * q8) + lo;
  int z = wg / gxy; int rem = wg - z * gxy;
  int by = rem / gx; int bx = rem - by * gx;

  int m0 = by * BM;
  int n0 = bx * BN;
  if (MODE == 3 && n0 > m0 + (BM - 1)) return;  // fully-masked causal tile

  int head = z, kbeg = 0, kend = K;
  if (MODE == 4) {
    head = z >> 1;
    int kf = m0 + BM; if (kf > K) kf = K;   // causal K-limit (multiple of 128)
    int half = kf >> 1;                      // multiple of 64
    kbeg = (z & 1) * half; kend = kbeg + half;
    A += (size_t)head * sAz; B += (size_t)head * sBz;
  } else {
    A += (size_t)z * sAz; B += (size_t)z * sBz;
  }
  int nt = (kend - kbeg) >> 6;  // BK=64 steps

  // LDS: 2 buffers x (A[128][64] + B[128][64]) bf16 = 64KB. MODE3 bounce reuses it.
  __shared__ __align__(16) bf16_t smem[32768];

  int tid = threadIdx.x;
  int lane = tid & 63;
  int wave = tid >> 6;
  int wr = wave >> 1, wc = wave & 1;
  int l15 = lane & 15, lk = lane >> 4;

  // ---- staging source pointers: wave w covers rows w*32..w*32+31 (4 issues of 8 rows) ----
  // LDS is written linearly (base + lane*16B); swizzle is pre-applied to the GLOBAL
  // source: LDS slot (row, c') holds global chunk c' ^ (row&7), row&7 == lane>>3 here.
  int rsub = lane >> 3;                       // 0..7
  int csw = ((lane & 7) ^ rsub) * 8;          // element offset of source chunk
  const bf16_t* pA[4]; const bf16_t* pB[4];
  #pragma unroll
  for (int i = 0; i < 4; i++) {
    pA[i] = A + (size_t)(m0 + wave * 32 + i * 8 + rsub) * lda + kbeg + csw;
    pB[i] = B + (size_t)(n0 + wave * 32 + i * 8 + rsub) * ldb + kbeg + csw;
  }
  bf16_t* ldsA = smem + wave * 2048;          // element offset within A half
  bf16_t* ldsB = smem + 8192 + wave * 2048;   // B half at +8192 elements

#define STAGE(t, db)                                                     \
  do {                                                                   \
    int _ko = (t) * BKK;                                                 \
    bf16_t* _ba = ldsA + (db) * 16384;                                   \
    bf16_t* _bb = ldsB + (db) * 16384;                                   \
    _Pragma("unroll")                                                    \
    for (int _i = 0; _i < 4; _i++) GLDS16(pA[_i] + _ko, _ba + _i * 512); \
    _Pragma("unroll")                                                    \
    for (int _i = 0; _i < 4; _i++) GLDS16(pB[_i] + _ko, _bb + _i * 512); \
  } while (0)

  // ---- fragment read byte-offsets (same XOR swizzle), per k-half kk ----
  int aoffb[2][4], boffb[2][4];
  #pragma unroll
  for (int m = 0; m < 4; m++) {
    int ra = wr * 64 + m * 16 + l15;
    int rb = wc * 64 + m * 16 + l15;
    #pragma unroll
    for (int kk = 0; kk < 2; kk++) {
      aoffb[kk][m] = ra * 128 + (((kk * 4 + lk) ^ (ra & 7)) * 16);
      boffb[kk][m] = 16384 + rb * 128 + (((kk * 4 + lk) ^ (rb & 7)) * 16);
    }
  }

  f32x4 acc[4][4] = {};

  STAGE(0, 0);
  int cur = 0;
  for (int t = 0; t < nt; ++t) {
    if (t + 1 < nt) {
      STAGE(t + 1, cur ^ 1);
      asm volatile("s_waitcnt vmcnt(8)" ::: "memory");  // own 8 oldest (tile t) done
    } else {
      asm volatile("s_waitcnt vmcnt(0)" ::: "memory");
    }
    __builtin_amdgcn_s_barrier();                       // everyone's tile-t DMAs done
    const char* base = (const char*)smem + cur * 32768;
    #pragma unroll
    for (int kk = 0; kk < 2; kk++) {
      bf16x8 af[4], bfv[4];
      #pragma unroll
      for (int m = 0; m < 4; m++) af[m] = *(const bf16x8*)(base + aoffb[kk][m]);
      #pragma unroll
      for (int n = 0; n < 4; n++) bfv[n] = *(const bf16x8*)(base + boffb[kk][n]);
      #pragma unroll
      for (int m = 0; m < 4; m++)
        #pragma unroll
        for (int n = 0; n < 4; n++)
          acc[m][n] = __builtin_amdgcn_mfma_f32_16x16x32_bf16(af[m], bfv[n], acc[m][n], 0, 0, 0);
    }
    asm volatile("" ::: "memory");
    __builtin_amdgcn_s_barrier();                       // protect buf before next stage
    cur ^= 1;
  }
#undef STAGE

  int rbase = m0 + wr * 64;
  int cbase = n0 + wc * 64;
  if (MODE == 3) {
    const float* av = avec + z * sVz;
    const float* pv = pmvec + z * sVz;
    float* nr = nraw + z * sVz;
    bf16_t* Pp = P + z * sPz;
    const float ISQ = 0.04419417382415922f;  // 1/sqrt(512)
    #pragma unroll
    for (int m = 0; m < 4; m++) {
      float rsum[4] = {0, 0, 0, 0};
      #pragma unroll
      for (int n = 0; n < 4; n++) {
        int cg = cbase + n * 16 + l15;
        float aexp = av[cg];
        #pragma unroll
        for (int r = 0; r < 4; r++) {
          int rg = rbase + m * 16 + lk * 4 + r;
          float val = 0.f;
          if (cg <= rg) val = acc[m][n][r] * ISQ * __expf(aexp - pv[rg]);
          smem[(size_t)(wr * 64 + m * 16 + lk * 4 + r) * 136 + wc * 64 + n * 16 + l15] =
              (bf16_t)val;
          rsum[r] += val;
        }
      }
      #pragma unroll
      for (int r = 0; r < 4; r++) {
        float v = rsum[r];
        v += __shfl_xor(v, 1); v += __shfl_xor(v, 2); v += __shfl_xor(v, 4); v += __shfl_xor(v, 8);
        if (l15 == 0) atomicAdd(&nr[rbase + m * 16 + lk * 4 + r], v);
      }
    }
    __syncthreads();
    // coalesced bf16x8 stores of the bounced tile
    #pragma unroll
    for (int i = 0; i < 8; i++) {
      int chunk = tid + i * 256;          // 0..2047
      int row = chunk >> 4, cc = chunk & 15;
      *(bf16x8*)(Pp + (size_t)(m0 + row) * ldc + n0 + cc * 8) =
          *(const bf16x8*)(smem + (size_t)row * 136 + cc * 8);
    }
  } else {
    #pragma unroll
    for (int m = 0; m < 4; m++) {
      #pragma unroll
      for (int r = 0; r < 4; r++) {
        int rg = rbase + m * 16 + lk * 4 + r;
        float rowscale = (MODE == 4) ? scalev[head * sVz + rg] : 1.f;
        #pragma unroll
        for (int n = 0; n < 4; n++) {
          int cg = cbase + n * 16 + l15;
          size_t idx = (size_t)head * sCz + (size_t)rg * ldc + cg;
          float v = acc[m][n][r];
          if (MODE == 4) atomicAdd(&C[idx], v * rowscale);
          else if (MODE == 5) atomicAdd(&C[idx], v);
          else C[idx] = v;
        }
      }
    }
  }
}

extern "C" void kernel_launch(void* const* d_in, const int* in_sizes, int n_in,
                              void* d_out, int out_size, void* d_ws, size_t ws_size,
                              hipStream_t stream) {
  const float* tokens = (const float*)d_in[0];
  const float* ln_w   = (const float*)d_in[1];
  const float* up_w   = (const float*)d_in[2];
  const float* conv_w = (const float*)d_in[3];
  const float* conv_b = (const float*)d_in[4];
  const float* q_w    = (const float*)d_in[5];
  const float* k_w    = (const float*)d_in[6];
  const float* v_w    = (const float*)d_in[7];
  const float* ig_w   = (const float*)d_in[8];
  const float* ig_b   = (const float*)d_in[9];
  const float* fg_w   = (const float*)d_in[10];
  const float* fg_b   = (const float*)d_in[11];
  const float* skipw  = (const float*)d_in[12];
  const float* onormw = (const float*)d_in[13];
  const float* down_w = (const float*)d_in[14];
  const float* post_w = (const float*)d_in[15];
  const float* lat_w  = (const float*)d_in[16];
  const float* lat_b  = (const float*)d_in[17];
  const float* r1_w   = (const float*)d_in[18];
  const float* r1_b   = (const float*)d_in[19];
  const float* r2_w   = (const float*)d_in[20];
  const float* r2_b   = (const float*)d_in[21];
  const float* t1_w   = (const float*)d_in[22];
  const float* t1_b   = (const float*)d_in[23];
  const float* t2_w   = (const float*)d_in[24];
  const float* t2_b   = (const float*)d_in[25];

  char* ws = (char*)d_ws;
  size_t off = 0;
  auto alloc = [&](size_t bytes) -> char* {
    char* p = ws + off;
    off += (bytes + 255) & ~(size_t)255;
    return p;
  };
  float*  X    = (float*)alloc((size_t)S_LEN * DMODEL * 4);
  float*  UP   = (float*)alloc((size_t)S_LEN * UPCOLS * 4);   // reused as Chead at end
  float*  XC   = (float*)alloc((size_t)S_LEN * INNER * 4);
  float*  Hbuf = (float*)alloc((size_t)S_LEN * INNER * 4);
  bf16_t* XN   = (bf16_t*)alloc((size_t)S_LEN * DMODEL * 2);
  bf16_t* Qb   = (bf16_t*)alloc((size_t)S_LEN * INNER * 2);
  bf16_t* Kb   = (bf16_t*)alloc((size_t)S_LEN * INNER * 2);
  bf16_t* Vb   = (bf16_t*)alloc((size_t)S_LEN * INNER * 2);
  bf16_t* VT   = (bf16_t*)alloc((size_t)S_LEN * INNER * 2);
  bf16_t* Pb   = (bf16_t*)alloc((size_t)NHEAD * S_LEN * S_LEN * 2);
  bf16_t* OUTb = (bf16_t*)alloc((size_t)S_LEN * INNER * 2);
  bf16_t* Wb   = (bf16_t*)alloc((size_t)UPCOLS * DMODEL * 2);
  bf16_t* Wb2  = (bf16_t*)alloc((size_t)DMODEL * INNER * 2);
  float*  IG   = (float*)alloc(NHEAD * S_LEN * 4);
  float*  FG   = (float*)alloc(NHEAD * S_LEN * 4);
  float*  AV   = (float*)alloc(NHEAD * S_LEN * 4);
  float*  PM   = (float*)alloc(NHEAD * S_LEN * 4);
  float*  NF   = (float*)alloc(NHEAD * S_LEN * 4);
  float*  NRAW = (float*)alloc(NHEAD * S_LEN * 4);
  float*  SCL  = (float*)alloc(NHEAD * S_LEN * 4);
  float* Chead = UP;  // [2048][3072] f32 (24MB <= UP's 32MB), UP dead by then
  float* latent_out = (float*)d_out;
  float* reward_out = (float*)d_out + (size_t)S_LEN * DMODEL;
  float* term_out   = reward_out + S_LEN;

  if (off > ws_size) return;  // clean failure instead of OOB corruption

  hipMemcpyAsync(X, tokens, (size_t)S_LEN * DMODEL * 4, hipMemcpyDeviceToDevice, stream);

  for (int l = 0; l < NLAYER; l++) {
    ln_kernel<<<S_LEN, 256, 0, stream>>>(X, ln_w + l * DMODEL, XN);
    cvt_f32_bf16<<<1024, 256, 0, stream>>>(up_w + (size_t)l * UPCOLS * DMODEL, Wb,
                                           UPCOLS * DMODEL / 4);
    gemm_kernel<0><<<dim3(UPCOLS / BN, S_LEN / BM, 1), 256, 0, stream>>>(
        XN, DMODEL, 0, Wb, DMODEL, 0, UP, UPCOLS, 0, nullptr, 0,
        DMODEL, nullptr, nullptr, nullptr, nullptr, 0);
    conv_qkv_kernel<<<dim3(2, S_LEN), 256, 0, stream>>>(
        UP, conv_w + (size_t)l * INNER * 4, conv_b + l * INNER,
        q_w + (size_t)l * NBLK * 16, k_w + (size_t)l * NBLK * 16, v_w + (size_t)l * NBLK * 16,
        XC, Qb, Kb, Vb);
    transpose_bf16<<<dim3(64, 64), 256, 0, stream>>>(Vb, VT);
    gates_kernel<<<S_LEN, 256, 0, stream>>>(Qb, Kb, Vb, ig_w + (size_t)l * NHEAD * GIN,
                                            ig_b + l * NHEAD, fg_w + (size_t)l * NHEAD * GIN,
                                            fg_b + l * NHEAD, IG, FG);
    scan_kernel<<<NHEAD, 256, 0, stream>>>(IG, FG, AV, PM, NF);
    zero_f32<<<(NHEAD * S_LEN + 255) / 256, 256, 0, stream>>>(NRAW, NHEAD * S_LEN);
    gemm_kernel<3><<<dim3(S_LEN / BN, S_LEN / BM, NHEAD), 256, 0, stream>>>(
        Qb, INNER, DHEAD, Kb, INNER, DHEAD, nullptr, S_LEN, 0, Pb, (long long)S_LEN * S_LEN,
        DHEAD, AV, PM, NRAW, nullptr, S_LEN);
    scale_kernel<<<(NHEAD * S_LEN + 255) / 256, 256, 0, stream>>>(NRAW, NF, SCL, NHEAD * S_LEN);
    zero4_f32<<<2048, 256, 0, stream>>>(Hbuf, (int)((size_t)S_LEN * INNER / 4));
    gemm_kernel<4><<<dim3(DHEAD / BN, S_LEN / BM, 2 * NHEAD), 256, 0, stream>>>(
        Pb, S_LEN, (long long)S_LEN * S_LEN, VT, S_LEN, (long long)DHEAD * S_LEN,
        Hbuf, INNER, DHEAD, nullptr, 0,
        S_LEN, nullptr, nullptr, nullptr, SCL, S_LEN);
    onorm_kernel<<<dim3(NHEAD, S_LEN), 256, 0, stream>>>(Hbuf, XC, UP, onormw + l * INNER,
                                                         skipw + l * INNER, OUTb);
    cvt_f32_bf16<<<1024, 256, 0, stream>>>(down_w + (size_t)l * DMODEL * INNER, Wb2,
                                           DMODEL * INNER / 4);
    gemm_kernel<5><<<dim3(DMODEL / BN, S_LEN / BM, 2), 256, 0, stream>>>(
        OUTb, INNER, DMODEL, Wb2, INNER, DMODEL, X, DMODEL, 0, nullptr, 0,
        DMODEL, nullptr, nullptr, nullptr, nullptr, 0);
  }

  // final heads: one merged GEMM over [lat | r1 | t1]  (N = 3072)
  ln_kernel<<<S_LEN, 256, 0, stream>>>(X, post_w, XN);
  bf16_t* Wh = Wb;  // [3072][1024] bf16
  cvt_f32_bf16<<<512, 256, 0, stream>>>(lat_w, Wh, DMODEL * DMODEL / 4);
  cvt_f32_bf16<<<512, 256, 0, stream>>>(r1_w, Wh + (size_t)DMODEL * DMODEL, DMODEL * DMODEL / 4);
  cvt_f32_bf16<<<512, 256, 0, stream>>>(t1_w, Wh + 2 * (size_t)DMODEL * DMODEL,
                                        DMODEL * DMODEL / 4);
  gemm_kernel<0><<<dim3(3072 / BN, S_LEN / BM, 1), 256, 0, stream>>>(
      XN, DMODEL, 0, Wh, DMODEL, 0, Chead, 3072, 0, nullptr, 0,
      DMODEL, nullptr, nullptr, nullptr, nullptr, 0);
  latcopy_kernel<<<S_LEN, 256, 0, stream>>>(Chead, lat_b, latent_out);
  rt_kernel<<<S_LEN, 256, 0, stream>>>(Chead, r1_b, t1_b, r2_w, r2_b, t2_w, t2_b,
                                       reward_out, term_out);
}

// Round 5
// 962.108 us; speedup vs baseline: 1.4695x; 1.0908x over previous
//
#include <hip/hip_runtime.h>
#include <hip/hip_bf16.h>
#include <math.h>
#include <cstdint>

typedef __bf16 bf16_t;
typedef bf16_t bf16x8 __attribute__((ext_vector_type(8)));
typedef bf16_t bf16x4 __attribute__((ext_vector_type(4)));
typedef bf16_t bf16x2 __attribute__((ext_vector_type(2)));
typedef float f32x4 __attribute__((ext_vector_type(4)));
typedef float f32x2 __attribute__((ext_vector_type(2)));

#define S_LEN 2048
#define DMODEL 1024
#define NLAYER 4
#define NHEAD 4
#define INNER 2048
#define DHEAD 512
#define NBLK 512
#define UPCOLS 4096
#define GIN 6144

// global -> LDS direct DMA, 16B per lane. Size must be a literal -> macro.
#define GLDS16(gp, lp)                                              \
  __builtin_amdgcn_global_load_lds(                                 \
      (const __attribute__((address_space(1))) void*)(gp),          \
      (__attribute__((address_space(3))) void*)(lp), 16, 0, 0)

// ---------------- zero f32 buffer ----------------
__global__ void zero_f32(float* __restrict__ p, int n) {
  int i = blockIdx.x * 256 + threadIdx.x;
  if (i < n) p[i] = 0.f;
}

// ---------------- convert f32 -> bf16 (vectorized, grid-stride) ----------------
__global__ __launch_bounds__(256) void cvt_f32_bf16(const float* __restrict__ in,
                                                    bf16_t* __restrict__ out, int n4) {
  int i = blockIdx.x * 256 + threadIdx.x;
  int stride = gridDim.x * 256;
  for (; i < n4; i += stride) {
    f32x4 v = ((const f32x4*)in)[i];
    bf16x4 o;
    #pragma unroll
    for (int j = 0; j < 4; j++) o[j] = (bf16_t)v[j];
    ((bf16x4*)out)[i] = o;
  }
}

// ---------------- fused: X = src (+ p0 + p1); LN(X) -> bf16 XN ----------------
__global__ __launch_bounds__(256) void ln_fused(const float* src, const float* p0,
                                                const float* p1, const float* __restrict__ w,
                                                float* Xout, bf16_t* __restrict__ out) {
  int s = blockIdx.x;
  int t = threadIdx.x;
  size_t base = (size_t)s * DMODEL;
  f32x4 v = ((const f32x4*)(src + base))[t];
  if (p0) {
    f32x4 a = ((const f32x4*)(p0 + base))[t];
    f32x4 b = ((const f32x4*)(p1 + base))[t];
    #pragma unroll
    for (int j = 0; j < 4; j++) v[j] += a[j] + b[j];
  }
  ((f32x4*)(Xout + base))[t] = v;
  float s1 = v[0] + v[1] + v[2] + v[3];
  float s2 = v[0]*v[0] + v[1]*v[1] + v[2]*v[2] + v[3]*v[3];
  __shared__ float b1[4], b2[4];
  #pragma unroll
  for (int off = 32; off; off >>= 1) { s1 += __shfl_xor(s1, off); s2 += __shfl_xor(s2, off); }
  if ((t & 63) == 0) { b1[t >> 6] = s1; b2[t >> 6] = s2; }
  __syncthreads();
  float tot1 = b1[0] + b1[1] + b1[2] + b1[3];
  float tot2 = b2[0] + b2[1] + b2[2] + b2[3];
  float mu = tot1 * (1.f / DMODEL);
  float var = tot2 * (1.f / DMODEL) - mu * mu;
  float rs = rsqrtf(var + 1e-5f);
  bf16x4 o;
  #pragma unroll
  for (int j = 0; j < 4; j++) o[j] = (bf16_t)((v[j] - mu) * rs * w[t * 4 + j]);
  ((bf16x4*)(out + base))[t] = o;
}

// ---------------- causal conv(K=4)+silu + blockwise q/k/v ----------------
__global__ __launch_bounds__(256) void conv_qkv_kernel(
    const float* __restrict__ UP, const float* __restrict__ cw, const float* __restrict__ cb,
    const float* __restrict__ qw, const float* __restrict__ kw, const float* __restrict__ vw,
    float* __restrict__ XC, bf16_t* __restrict__ Q, bf16_t* __restrict__ Kb, bf16_t* __restrict__ V) {
  int s = blockIdx.y;
  int n = blockIdx.x * 256 + threadIdx.x;  // 0..511
  int c0 = n * 4;
  f32x4 zero4 = {};
  f32x4 xm[4];
  #pragma unroll
  for (int k = 0; k < 4; k++) {
    int sr = s + k - 3;
    xm[k] = (sr >= 0) ? *(const f32x4*)(UP + (size_t)sr * UPCOLS + c0) : zero4;
  }
  f32x4 cbv = *(const f32x4*)(cb + c0);
  float xc[4];
  #pragma unroll
  for (int d = 0; d < 4; d++) {
    f32x4 wv = *(const f32x4*)(cw + (size_t)(c0 + d) * 4);
    float a = cbv[d];
    #pragma unroll
    for (int k = 0; k < 4; k++) a += wv[k] * xm[k][d];
    xc[d] = a / (1.f + __expf(-a));  // silu
  }
  f32x4 xcv; xcv[0]=xc[0]; xcv[1]=xc[1]; xcv[2]=xc[2]; xcv[3]=xc[3];
  *(f32x4*)(XC + (size_t)s * INNER + c0) = xcv;
  bf16x4 qo, ko, vo;
  #pragma unroll
  for (int o = 0; o < 4; o++) {
    float aq = 0, ak = 0, av = 0;
    #pragma unroll
    for (int d = 0; d < 4; d++) {
      aq += qw[n * 16 + o * 4 + d] * xc[d];
      ak += kw[n * 16 + o * 4 + d] * xc[d];
      av += vw[n * 16 + o * 4 + d] * xm[3][d];  // v from pre-conv xm
    }
    qo[o] = (bf16_t)aq; ko[o] = (bf16_t)ak; vo[o] = (bf16_t)av;
  }
  ((bf16x4*)(Q  + (size_t)s * INNER))[n] = qo;
  ((bf16x4*)(Kb + (size_t)s * INNER))[n] = ko;
  ((bf16x4*)(V  + (size_t)s * INNER))[n] = vo;
}

// ---------------- bf16 transpose 2048x2048 ----------------
__global__ __launch_bounds__(256) void transpose_bf16(const bf16_t* __restrict__ in,
                                                      bf16_t* __restrict__ out) {
  __shared__ bf16_t tile[32][33];
  int c0 = blockIdx.x * 32, r0 = blockIdx.y * 32;
  int tx = threadIdx.x & 31, ty = threadIdx.x >> 5;
  #pragma unroll
  for (int i = ty; i < 32; i += 8) tile[i][tx] = in[(size_t)(r0 + i) * INNER + c0 + tx];
  __syncthreads();
  #pragma unroll
  for (int i = ty; i < 32; i += 8) out[(size_t)(c0 + i) * S_LEN + r0 + tx] = tile[tx][i];
}

// ---------------- input/forget gate logits ----------------
__global__ __launch_bounds__(256) void gates_kernel(
    const bf16_t* __restrict__ Q, const bf16_t* __restrict__ K, const bf16_t* __restrict__ V,
    const float* __restrict__ igw, const float* __restrict__ igb,
    const float* __restrict__ fgw, const float* __restrict__ fgb,
    float* __restrict__ IG, float* __restrict__ FG) {
  int s = blockIdx.x;
  float pi[NHEAD] = {0, 0, 0, 0}, pf[NHEAD] = {0, 0, 0, 0};
  for (int e = threadIdx.x; e < GIN; e += 256) {
    float g;
    if (e < INNER)            g = (float)Q[(size_t)s * INNER + e];
    else if (e < 2 * INNER)   g = (float)K[(size_t)s * INNER + e - INNER];
    else                      g = (float)V[(size_t)s * INNER + e - 2 * INNER];
    #pragma unroll
    for (int h = 0; h < NHEAD; h++) {
      pi[h] += g * igw[h * GIN + e];
      pf[h] += g * fgw[h * GIN + e];
    }
  }
  __shared__ float red[8][4];
  #pragma unroll
  for (int h = 0; h < NHEAD; h++) {
    float a = pi[h], b = pf[h];
    #pragma unroll
    for (int off = 32; off; off >>= 1) { a += __shfl_xor(a, off); b += __shfl_xor(b, off); }
    if ((threadIdx.x & 63) == 0) { red[h][threadIdx.x >> 6] = a; red[h + 4][threadIdx.x >> 6] = b; }
  }
  __syncthreads();
  if (threadIdx.x < NHEAD) {
    int h = threadIdx.x;
    IG[h * S_LEN + s] = red[h][0] + red[h][1] + red[h][2] + red[h][3] + igb[h];
    FG[h * S_LEN + s] = red[h + 4][0] + red[h + 4][1] + red[h + 4][2] + red[h + 4][3] + fgb[h];
  }
}

// ---------------- per-head scan: cs=cumsum(logsig(fg)), a=ig-cs, pm=prefmax(a), nf=exp(-(cs+pm)) ----
__global__ __launch_bounds__(256) void scan_kernel(const float* __restrict__ IG,
                                                   const float* __restrict__ FG,
                                                   float* __restrict__ AV, float* __restrict__ PM,
                                                   float* __restrict__ NF) {
  int h = blockIdx.x;
  int tid = threadIdx.x;
  const float* fg = FG + h * S_LEN;
  const float* ig = IG + h * S_LEN;
  float cs[8];
  float run = 0.f;
  #pragma unroll
  for (int i = 0; i < 8; i++) {
    float x = fg[tid * 8 + i];
    float l = (x >= 0.f) ? -log1pf(__expf(-x)) : (x - log1pf(__expf(x)));
    run += l; cs[i] = run;
  }
  __shared__ float sb[256];
  sb[tid] = run;
  __syncthreads();
  for (int off = 1; off < 256; off <<= 1) {
    float add = (tid >= off) ? sb[tid - off] : 0.f;
    __syncthreads();
    sb[tid] += add;
    __syncthreads();
  }
  float base = sb[tid] - run;  // exclusive prefix sum
  float a[8];
  float runm = -__builtin_inff();
  #pragma unroll
  for (int i = 0; i < 8; i++) {
    cs[i] += base;
    a[i] = ig[tid * 8 + i] - cs[i];
    runm = fmaxf(runm, a[i]);
  }
  __syncthreads();
  sb[tid] = runm;
  __syncthreads();
  for (int off = 1; off < 256; off <<= 1) {
    float other = (tid >= off) ? sb[tid - off] : -__builtin_inff();
    __syncthreads();
    sb[tid] = fmaxf(sb[tid], other);
    __syncthreads();
  }
  float rm = (tid == 0) ? -__builtin_inff() : sb[tid - 1];  // exclusive prefix max
  #pragma unroll
  for (int i = 0; i < 8; i++) {
    rm = fmaxf(rm, a[i]);
    AV[h * S_LEN + tid * 8 + i] = a[i];
    PM[h * S_LEN + tid * 8 + i] = rm;
    NF[h * S_LEN + tid * 8 + i] = __expf(-(cs[i] + rm));
  }
}

// ---------------- n = max(|nraw|, nf); scale = 1/(n+1e-6) ----------------
__global__ void scale_kernel(const float* __restrict__ nraw, const float* __restrict__ nf,
                             float* __restrict__ scale, int n) {
  int i = blockIdx.x * 256 + threadIdx.x;
  if (i < n) scale[i] = 1.f / (fmaxf(fabsf(nraw[i]), nf[i]) + 1e-6f);
}

// ---------------- per-head LN over DH (reads Hp0+Hp1) + skip*xc, * silu(z) -> bf16 ----------------
__global__ __launch_bounds__(256) void onorm_kernel(
    const float* __restrict__ Hp0, const float* __restrict__ Hp1,
    const float* __restrict__ XC, const float* __restrict__ UP,
    const float* __restrict__ onw, const float* __restrict__ skipw, bf16_t* __restrict__ OUT) {
  int h = blockIdx.x, s = blockIdx.y;
  int c = h * DHEAD + threadIdx.x * 2;
  size_t idx = (size_t)s * INNER + c;
  f32x2 v0 = *(const f32x2*)(Hp0 + idx);
  f32x2 v1 = *(const f32x2*)(Hp1 + idx);
  f32x2 v; v[0] = v0[0] + v1[0]; v[1] = v0[1] + v1[1];
  float s1 = v[0] + v[1], s2 = v[0] * v[0] + v[1] * v[1];
  __shared__ float b1[4], b2[4];
  #pragma unroll
  for (int off = 32; off; off >>= 1) { s1 += __shfl_xor(s1, off); s2 += __shfl_xor(s2, off); }
  if ((threadIdx.x & 63) == 0) { b1[threadIdx.x >> 6] = s1; b2[threadIdx.x >> 6] = s2; }
  __syncthreads();
  float tot1 = b1[0] + b1[1] + b1[2] + b1[3];
  float tot2 = b2[0] + b2[1] + b2[2] + b2[3];
  float mu = tot1 * (1.f / DHEAD);
  float var = tot2 * (1.f / DHEAD) - mu * mu;
  float rs = rsqrtf(var + 1e-5f);
  bf16x2 o;
  #pragma unroll
  for (int j = 0; j < 2; j++) {
    float val = (v[j] - mu) * rs * onw[c + j] + skipw[c + j] * XC[idx + j];
    float z = UP[(size_t)s * UPCOLS + INNER + c + j];
    val *= z / (1.f + __expf(-z));
    o[j] = (bf16_t)val;
  }
  *(bf16x2*)(OUT + idx) = o;
}

// ---------------- latent slice copy + bias ----------------
__global__ __launch_bounds__(256) void latcopy_kernel(const float* __restrict__ Ch,
                                                      const float* __restrict__ b,
                                                      float* __restrict__ out) {
  int s = blockIdx.x, t = threadIdx.x;
  f32x4 v = ((const f32x4*)(Ch + (size_t)s * 3072))[t];
  f32x4 bb = ((const f32x4*)b)[t];
  f32x4 o; o[0]=v[0]+bb[0]; o[1]=v[1]+bb[1]; o[2]=v[2]+bb[2]; o[3]=v[3]+bb[3];
  ((f32x4*)(out + (size_t)s * DMODEL))[t] = o;
}

// ---------------- reward/term: row dot over D (reads merged head buffer) ----------------
__global__ __launch_bounds__(256) void rt_kernel(
    const float* __restrict__ Ch,
    const float* __restrict__ r1b, const float* __restrict__ t1b,
    const float* __restrict__ r2w, const float* __restrict__ r2b,
    const float* __restrict__ t2w, const float* __restrict__ t2b,
    float* __restrict__ outR, float* __restrict__ outT) {
  int s = blockIdx.x, t = threadIdx.x;
  f32x4 a = ((const f32x4*)(Ch + (size_t)s * 3072 + 1024))[t];
  f32x4 b = ((const f32x4*)(Ch + (size_t)s * 3072 + 2048))[t];
  f32x4 ab = ((const f32x4*)r1b)[t];
  f32x4 bb = ((const f32x4*)t1b)[t];
  f32x4 w1 = ((const f32x4*)r2w)[t];
  f32x4 w2 = ((const f32x4*)t2w)[t];
  float pr = 0, pt = 0;
  #pragma unroll
  for (int j = 0; j < 4; j++) {
    pr += (a[j] + ab[j]) * w1[j];
    pt += (b[j] + bb[j]) * w2[j];
  }
  __shared__ float rb[4], tb[4];
  #pragma unroll
  for (int off = 32; off; off >>= 1) { pr += __shfl_xor(pr, off); pt += __shfl_xor(pt, off); }
  if ((t & 63) == 0) { rb[t >> 6] = pr; tb[t >> 6] = pt; }
  __syncthreads();
  if (t == 0) {
    outR[s] = rb[0] + rb[1] + rb[2] + rb[3] + r2b[0];
    outT[s] = tb[0] + tb[1] + tb[2] + tb[3] + t2b[0];
  }
}

// ================= bf16 MFMA NT GEMM, 128x128 tile, BK=32, T3-min pipeline =================
// Per K-step: STAGE(t+1 -> other buf) ; ds_read(cur) ; lgkmcnt(0) ; MFMA ;
//             vmcnt(0) ; ONE s_barrier.  Stage latency hides under ds_read+MFMA.
// 32KB LDS (2 x 16KB buffers) -> ~4 blocks/CU for cross-block latency hiding (m114).
// Swizzle: LDS linear dest (DMA rule); global source chunk = c' ^ ((row>>1)&3);
// ds_read applies the same XOR -> 2 lanes/bank (free, m136).
// MODE 0: C = A*B^T (plain store)
// MODE 3: QK^T decay epilogue -> P bf16 (LDS bounce) + row-sum atomics; triangular grid
// MODE 4: PV causal, split-K over z&1 -> plain store to partial buffer C + (z&1)*sPz
// MODE 6: K-split over z -> plain store to partial buffer C + z*sPz
#define BM 128
#define BN 128

template <int MODE>
__global__ __launch_bounds__(256) void gemm_kernel(
    const bf16_t* __restrict__ A, int lda, long long sAz,
    const bf16_t* __restrict__ B, int ldb, long long sBz,
    float* __restrict__ C, int ldc, long long sCz,
    bf16_t* __restrict__ P, long long sPz,
    int K,
    const float* __restrict__ avec, const float* __restrict__ pmvec,
    float* __restrict__ nraw,
    const float* __restrict__ scalev, long long sVz) {
  // ---- bijective XCD swizzle (m204) over the flattened grid ----
  int gx = gridDim.x, gxy = gx * gridDim.y;
  int nwg = gxy * gridDim.z;
  int orig = blockIdx.z * gxy + blockIdx.y * gx + blockIdx.x;
  int xcd = orig & 7, lo = orig >> 3;
  int q8 = nwg >> 3, r8 = nwg & 7;
  int wg = (xcd < r8 ? xcd * (q8 + 1) : r8 * (q8 + 1) + (xcd - r8) * q8) + lo;
  int z = wg / gxy; int rem = wg - z * gxy;
  int by, bx;
  if (MODE == 3) {  // triangular decode: rem -> (by, bx<=by), 136 tiles
    by = (int)((sqrtf(8.f * (float)rem + 1.f) - 1.f) * 0.5f);
    while ((by + 1) * (by + 2) / 2 <= rem) by++;
    while (by * (by + 1) / 2 > rem) by--;
    bx = rem - by * (by + 1) / 2;
  } else {
    by = rem / gx; bx = rem - by * gx;
  }
  int m0 = by * BM;
  int n0 = bx * BN;

  int head = z, kbeg = 0, kend = K;
  if (MODE == 4) {
    head = z >> 1;
    int kf = m0 + BM; if (kf > K) kf = K;   // causal K-limit (multiple of 128)
    int half = kf >> 1;                      // multiple of 64
    kbeg = (z & 1) * half; kend = kbeg + half;
    A += (size_t)head * sAz; B += (size_t)head * sBz;
  } else if (MODE == 6) {
    head = 0;
    int half = K >> 1;
    kbeg = z * half; kend = kbeg + half;
  } else {
    A += (size_t)z * sAz; B += (size_t)z * sBz;
  }
  int nt = (kend - kbeg) >> 5;  // BK=32 steps

  // LDS: 2 buffers x (A[128][32]+B[128][32]) = 32KB; MODE3 bounce needs 128*136 elems.
  constexpr int SME = (MODE == 3) ? (128 * 136) : 16384;
  __shared__ __align__(16) bf16_t smem[SME];

  int tid = threadIdx.x;
  int lane = tid & 63;
  int wave = tid >> 6;
  int wr = wave >> 1, wc = wave & 1;
  int l15 = lane & 15, lk = lane >> 4;

  // ---- staging: wave w covers rows w*32..w*32+31 (2 issues of 16 rows per matrix) ----
  // source chunk for lane = (lane&3) ^ ((row>>1)&3) pre-applied to GLOBAL address
  int csw = ((lane & 3) ^ ((lane >> 3) & 3)) * 8;
  const bf16_t* pA0 = A + (size_t)(m0 + wave * 32 + (lane >> 2)) * lda + kbeg + csw;
  const bf16_t* pA1 = pA0 + (size_t)16 * lda;
  const bf16_t* pB0 = B + (size_t)(n0 + wave * 32 + (lane >> 2)) * ldb + kbeg + csw;
  const bf16_t* pB1 = pB0 + (size_t)16 * ldb;
  bf16_t* ldsA = smem + wave * 1024;         // 32 rows x 32 elem per wave
  bf16_t* ldsB = smem + 4096 + wave * 1024;  // B half at +4096 elem

#define STAGE(t, db)                                   \
  do {                                                 \
    int _ko = (t) * 32;                                \
    bf16_t* _ba = ldsA + (db) * 8192;                  \
    bf16_t* _bb = ldsB + (db) * 8192;                  \
    GLDS16(pA0 + _ko, _ba);                            \
    GLDS16(pA1 + _ko, _ba + 512);                      \
    GLDS16(pB0 + _ko, _bb);                            \
    GLDS16(pB1 + _ko, _bb + 512);                      \
  } while (0)

  // ---- fragment read byte-offsets (same XOR swizzle) ----
  int aoff[4], boff[4];
  #pragma unroll
  for (int m = 0; m < 4; m++) {
    int ra = wr * 64 + m * 16 + l15;
    aoff[m] = ra * 64 + ((lk ^ ((ra >> 1) & 3)) * 16);
    int rb = wc * 64 + m * 16 + l15;
    boff[m] = 8192 + rb * 64 + ((lk ^ ((rb >> 1) & 3)) * 16);
  }

  f32x4 acc[4][4] = {};

  STAGE(0, 0);
  asm volatile("s_waitcnt vmcnt(0)" ::: "memory");
  __builtin_amdgcn_s_barrier();
  int cur = 0;
  for (int t = 0; t < nt; ++t) {
    if (t + 1 < nt) STAGE(t + 1, cur ^ 1);   // issue next tile first (T14 issue-early)
    __builtin_amdgcn_sched_barrier(0);
    const char* base = (const char*)smem + cur * 16384;
    bf16x8 af[4], bfv[4];
    #pragma unroll
    for (int m = 0; m < 4; m++) af[m] = *(const bf16x8*)(base + aoff[m]);
    #pragma unroll
    for (int n = 0; n < 4; n++) bfv[n] = *(const bf16x8*)(base + boff[n]);
    asm volatile("s_waitcnt lgkmcnt(0)" ::: "memory");
    __builtin_amdgcn_sched_barrier(0);       // rule 18: no MFMA hoist above the wait
    __builtin_amdgcn_s_setprio(1);
    #pragma unroll
    for (int m = 0; m < 4; m++)
      #pragma unroll
      for (int n = 0; n < 4; n++)
        acc[m][n] = __builtin_amdgcn_mfma_f32_16x16x32_bf16(af[m], bfv[n], acc[m][n], 0, 0, 0);
    __builtin_amdgcn_s_setprio(0);
    asm volatile("s_waitcnt vmcnt(0)" ::: "memory");  // stage(t+1) landed (hidden under MFMA)
    __builtin_amdgcn_s_barrier();                     // one barrier per K-step
    cur ^= 1;
  }
#undef STAGE

  int rbase = m0 + wr * 64;
  int cbase = n0 + wc * 64;
  if (MODE == 3) {
    const float* av = avec + z * sVz;
    const float* pv = pmvec + z * sVz;
    float* nr = nraw + z * sVz;
    bf16_t* Pp = P + z * sPz;
    const float ISQ = 0.04419417382415922f;  // 1/sqrt(512)
    #pragma unroll
    for (int m = 0; m < 4; m++) {
      float rsum[4] = {0, 0, 0, 0};
      #pragma unroll
      for (int n = 0; n < 4; n++) {
        int cg = cbase + n * 16 + l15;
        float aexp = av[cg];
        #pragma unroll
        for (int r = 0; r < 4; r++) {
          int rg = rbase + m * 16 + lk * 4 + r;
          float val = 0.f;
          if (cg <= rg) val = acc[m][n][r] * ISQ * __expf(aexp - pv[rg]);
          smem[(size_t)(wr * 64 + m * 16 + lk * 4 + r) * 136 + wc * 64 + n * 16 + l15] =
              (bf16_t)val;
          rsum[r] += val;
        }
      }
      #pragma unroll
      for (int r = 0; r < 4; r++) {
        float v = rsum[r];
        v += __shfl_xor(v, 1); v += __shfl_xor(v, 2); v += __shfl_xor(v, 4); v += __shfl_xor(v, 8);
        if (l15 == 0) atomicAdd(&nr[rbase + m * 16 + lk * 4 + r], v);
      }
    }
    __syncthreads();
    // coalesced bf16x8 stores of the bounced tile
    #pragma unroll
    for (int i = 0; i < 8; i++) {
      int chunk = tid + i * 256;          // 0..2047
      int row = chunk >> 4, cc = chunk & 15;
      *(bf16x8*)(Pp + (size_t)(m0 + row) * ldc + n0 + cc * 8) =
          *(const bf16x8*)(smem + (size_t)row * 136 + cc * 8);
    }
  } else {
    float* Cp = C;
    if (MODE == 4) Cp = C + (size_t)head * sCz + (size_t)(z & 1) * sPz;
    else if (MODE == 6) Cp = C + (size_t)z * sPz;
    else Cp = C + (size_t)head * sCz;
    #pragma unroll
    for (int m = 0; m < 4; m++) {
      #pragma unroll
      for (int r = 0; r < 4; r++) {
        int rg = rbase + m * 16 + lk * 4 + r;
        float rowscale = (MODE == 4) ? scalev[head * sVz + rg] : 1.f;
        #pragma unroll
        for (int n = 0; n < 4; n++) {
          int cg = cbase + n * 16 + l15;
          size_t idx = (size_t)rg * ldc + cg;
          float v = acc[m][n][r];
          if (MODE == 4) Cp[idx] = v * rowscale;
          else Cp[idx] = v;
        }
      }
    }
  }
}

extern "C" void kernel_launch(void* const* d_in, const int* in_sizes, int n_in,
                              void* d_out, int out_size, void* d_ws, size_t ws_size,
                              hipStream_t stream) {
  const float* tokens = (const float*)d_in[0];
  const float* ln_w   = (const float*)d_in[1];
  const float* up_w   = (const float*)d_in[2];
  const float* conv_w = (const float*)d_in[3];
  const float* conv_b = (const float*)d_in[4];
  const float* q_w    = (const float*)d_in[5];
  const float* k_w    = (const float*)d_in[6];
  const float* v_w    = (const float*)d_in[7];
  const float* ig_w   = (const float*)d_in[8];
  const float* ig_b   = (const float*)d_in[9];
  const float* fg_w   = (const float*)d_in[10];
  const float* fg_b   = (const float*)d_in[11];
  const float* skipw  = (const float*)d_in[12];
  const float* onormw = (const float*)d_in[13];
  const float* down_w = (const float*)d_in[14];
  const float* post_w = (const float*)d_in[15];
  const float* lat_w  = (const float*)d_in[16];
  const float* lat_b  = (const float*)d_in[17];
  const float* r1_w   = (const float*)d_in[18];
  const float* r1_b   = (const float*)d_in[19];
  const float* r2_w   = (const float*)d_in[20];
  const float* r2_b   = (const float*)d_in[21];
  const float* t1_w   = (const float*)d_in[22];
  const float* t1_b   = (const float*)d_in[23];
  const float* t2_w   = (const float*)d_in[24];
  const float* t2_b   = (const float*)d_in[25];

  char* ws = (char*)d_ws;
  size_t off = 0;
  auto alloc = [&](size_t bytes) -> char* {
    char* p = ws + off;
    off += (bytes + 255) & ~(size_t)255;
    return p;
  };
  float*  X    = (float*)alloc((size_t)S_LEN * DMODEL * 4);
  float*  UP   = (float*)alloc((size_t)S_LEN * UPCOLS * 4);   // reused as Chead at end
  float*  XC   = (float*)alloc((size_t)S_LEN * INNER * 4);
  float*  Hp0  = (float*)alloc((size_t)S_LEN * INNER * 4);    // PV partial 0 / down partials alias
  float*  Hp1  = (float*)alloc((size_t)S_LEN * INNER * 4);    // PV partial 1
  bf16_t* XN   = (bf16_t*)alloc((size_t)S_LEN * DMODEL * 2);
  bf16_t* Qb   = (bf16_t*)alloc((size_t)S_LEN * INNER * 2);
  bf16_t* Kb   = (bf16_t*)alloc((size_t)S_LEN * INNER * 2);
  bf16_t* Vb   = (bf16_t*)alloc((size_t)S_LEN * INNER * 2);
  bf16_t* VT   = (bf16_t*)alloc((size_t)S_LEN * INNER * 2);
  bf16_t* Pb   = (bf16_t*)alloc((size_t)NHEAD * S_LEN * S_LEN * 2);
  bf16_t* OUTb = (bf16_t*)alloc((size_t)S_LEN * INNER * 2);
  bf16_t* Wb   = (bf16_t*)alloc((size_t)UPCOLS * DMODEL * 2);
  bf16_t* Wb2  = (bf16_t*)alloc((size_t)DMODEL * INNER * 2);
  float*  IG   = (float*)alloc(NHEAD * S_LEN * 4);
  float*  FG   = (float*)alloc(NHEAD * S_LEN * 4);
  float*  AV   = (float*)alloc(NHEAD * S_LEN * 4);
  float*  PM   = (float*)alloc(NHEAD * S_LEN * 4);
  float*  NF   = (float*)alloc(NHEAD * S_LEN * 4);
  float*  NRAW = (float*)alloc(NHEAD * S_LEN * 4);
  float*  SCL  = (float*)alloc(NHEAD * S_LEN * 4);
  // down-proj partials alias Hp0 (dead after onorm; revived after down GEMM)
  float* Dp0 = Hp0;
  float* Dp1 = Hp0 + (size_t)S_LEN * DMODEL;
  float* Chead = UP;  // [2048][3072] f32 (24MB <= UP's 32MB), UP dead by then
  float* latent_out = (float*)d_out;
  float* reward_out = (float*)d_out + (size_t)S_LEN * DMODEL;
  float* term_out   = reward_out + S_LEN;

  if (off > ws_size) return;  // clean failure instead of OOB corruption

  for (int l = 0; l < NLAYER; l++) {
    // X = (l==0 ? tokens : X + Dp0 + Dp1); XN = LN(X)
    ln_fused<<<S_LEN, 256, 0, stream>>>(l == 0 ? tokens : X, l == 0 ? nullptr : Dp0,
                                        l == 0 ? nullptr : Dp1, ln_w + l * DMODEL, X, XN);
    cvt_f32_bf16<<<1024, 256, 0, stream>>>(up_w + (size_t)l * UPCOLS * DMODEL, Wb,
                                           UPCOLS * DMODEL / 4);
    gemm_kernel<0><<<dim3(UPCOLS / BN, S_LEN / BM, 1), 256, 0, stream>>>(
        XN, DMODEL, 0, Wb, DMODEL, 0, UP, UPCOLS, 0, nullptr, 0,
        DMODEL, nullptr, nullptr, nullptr, nullptr, 0);
    conv_qkv_kernel<<<dim3(2, S_LEN), 256, 0, stream>>>(
        UP, conv_w + (size_t)l * INNER * 4, conv_b + l * INNER,
        q_w + (size_t)l * NBLK * 16, k_w + (size_t)l * NBLK * 16, v_w + (size_t)l * NBLK * 16,
        XC, Qb, Kb, Vb);
    transpose_bf16<<<dim3(64, 64), 256, 0, stream>>>(Vb, VT);
    gates_kernel<<<S_LEN, 256, 0, stream>>>(Qb, Kb, Vb, ig_w + (size_t)l * NHEAD * GIN,
                                            ig_b + l * NHEAD, fg_w + (size_t)l * NHEAD * GIN,
                                            fg_b + l * NHEAD, IG, FG);
    scan_kernel<<<NHEAD, 256, 0, stream>>>(IG, FG, AV, PM, NF);
    zero_f32<<<(NHEAD * S_LEN + 255) / 256, 256, 0, stream>>>(NRAW, NHEAD * S_LEN);
    gemm_kernel<3><<<dim3(136, 1, NHEAD), 256, 0, stream>>>(
        Qb, INNER, DHEAD, Kb, INNER, DHEAD, nullptr, S_LEN, 0, Pb, (long long)S_LEN * S_LEN,
        DHEAD, AV, PM, NRAW, nullptr, S_LEN);
    scale_kernel<<<(NHEAD * S_LEN + 255) / 256, 256, 0, stream>>>(NRAW, NF, SCL, NHEAD * S_LEN);
    gemm_kernel<4><<<dim3(DHEAD / BN, S_LEN / BM, 2 * NHEAD), 256, 0, stream>>>(
        Pb, S_LEN, (long long)S_LEN * S_LEN, VT, S_LEN, (long long)DHEAD * S_LEN,
        Hp0, INNER, DHEAD, nullptr, (long long)S_LEN * INNER,
        S_LEN, nullptr, nullptr, nullptr, SCL, S_LEN);
    onorm_kernel<<<dim3(NHEAD, S_LEN), 256, 0, stream>>>(Hp0, Hp1, XC, UP, onormw + l * INNER,
                                                         skipw + l * INNER, OUTb);
    cvt_f32_bf16<<<1024, 256, 0, stream>>>(down_w + (size_t)l * DMODEL * INNER, Wb2,
                                           DMODEL * INNER / 4);
    gemm_kernel<6><<<dim3(DMODEL / BN, S_LEN / BM, 2), 256, 0, stream>>>(
        OUTb, INNER, 0, Wb2, INNER, 0, Dp0, DMODEL, 0, nullptr, (long long)S_LEN * DMODEL,
        INNER, nullptr, nullptr, nullptr, nullptr, 0);
  }

  // final heads: X += Dp0+Dp1 (layer 3 down), post-LN, one merged GEMM [lat | r1 | t1]
  ln_fused<<<S_LEN, 256, 0, stream>>>(X, Dp0, Dp1, post_w, X, XN);
  bf16_t* Wh = Wb;  // [3072][1024] bf16
  cvt_f32_bf16<<<512, 256, 0, stream>>>(lat_w, Wh, DMODEL * DMODEL / 4);
  cvt_f32_bf16<<<512, 256, 0, stream>>>(r1_w, Wh + (size_t)DMODEL * DMODEL, DMODEL * DMODEL / 4);
  cvt_f32_bf16<<<512, 256, 0, stream>>>(t1_w, Wh + 2 * (size_t)DMODEL * DMODEL,
                                        DMODEL * DMODEL / 4);
  gemm_kernel<0><<<dim3(3072 / BN, S_LEN / BM, 1), 256, 0, stream>>>(
      XN, DMODEL, 0, Wh, DMODEL, 0, Chead, 3072, 0, nullptr, 0,
      DMODEL, nullptr, nullptr, nullptr, nullptr, 0);
  latcopy_kernel<<<S_LEN, 256, 0, stream>>>(Chead, lat_b, latent_out);
  rt_kernel<<<S_LEN, 256, 0, stream>>>(Chead, r1_b, t1_b, r2_w, r2_b, t2_w, t2_b,
                                       reward_out, term_out);
}